// Round 1
// baseline (6918.102 us; speedup 1.0000x reference)
//
#include <hip/hip_runtime.h>
#include <cmath>

#define DEV __device__ __forceinline__

constexpr int kBW = 4096;          // B*W
constexpr int kM = 100, kF = 8, kN = 33, kH = 256, kGH = 128, kE = 64;

// ws offsets (in floats)
constexpr int OFF_ROWPTR  = 0;       // 34 int
constexpr int OFF_COLSRC  = 64;      // 64 int
constexpr int OFF_COLNORM = 128;     // 64 f
constexpr int OFF_C       = 192;     // 256 f (folded bias)
constexpr int OFF_WC      = 512;     // 128*256 f (post_w@fg_w)
constexpr int OFF_SPRE    = 33280;               // 4096*256 (s_pre -> s0 -> s1)
constexpr int OFF_GI      = OFF_SPRE + kBW * kH; // 4096*768
constexpr int OFF_SFUSE   = OFF_GI + kBW * 3 * kH;
constexpr int OFF_SGATE   = OFF_SFUSE + kBW * kH;
// total = 6,324,736 floats = 24.2 MB of ws

DEV float sigmoidf(float x) { return 1.0f / (1.0f + expf(-x)); }

// ---------------- graph prep: degree norm + CSR by dst (single thread, trivial) ----
__global__ void k_prep(const int* __restrict__ ei, const float* __restrict__ ew,
                       float* __restrict__ ws) {
  if (blockIdx.x != 0 || threadIdx.x != 0) return;
  int* rowptr = (int*)(ws + OFF_ROWPTR);
  int* colsrc = (int*)(ws + OFF_COLSRC);
  float* colnorm = ws + OFF_COLNORM;
  const int* src = ei;
  const int* dst = ei + kE;
  float deg[kN]; int cnt[kN];
  for (int n = 0; n < kN; ++n) { deg[n] = 0.f; cnt[n] = 0; }
  for (int e = 0; e < kE; ++e) { deg[dst[e]] += ew[e]; cnt[dst[e]]++; }
  float dinv[kN];
  for (int n = 0; n < kN; ++n) dinv[n] = deg[n] > 0.f ? 1.0f / sqrtf(deg[n]) : 0.f;
  int pos[kN];
  int run = 0;
  for (int n = 0; n < kN; ++n) { rowptr[n] = run; pos[n] = run; run += cnt[n]; }
  rowptr[kN] = run;
  for (int e = 0; e < kE; ++e) {
    int d = dst[e];
    int p = pos[d]++;
    colsrc[p] = src[e];
    colnorm[p] = dinv[src[e]] * ew[e] * dinv[d];
  }
}

// ---------------- fold Wc = post_w @ fg_w (128x256), c = post_b @ fg_w + fg_b -----
__global__ void k_wcfold(const float* __restrict__ post_w, const float* __restrict__ post_b,
                         const float* __restrict__ fg_w, const float* __restrict__ fg_b,
                         float* __restrict__ ws) {
  const int j = threadIdx.x;
  if ((int)blockIdx.x < kGH) {
    const int k = blockIdx.x;
    float a = 0.f;
    #pragma unroll 4
    for (int m = 0; m < kH; ++m) a = fmaf(post_w[k * kH + m], fg_w[m * kH + j], a);
    ws[OFF_WC + k * kH + j] = a;
  } else {
    float a = fg_b[j];
    #pragma unroll 4
    for (int m = 0; m < kH; ++m) a = fmaf(post_b[m], fg_w[m * kH + j], a);
    ws[OFF_C + j] = a;
  }
}

// ---------------- temporal pre-MLP: s = relu(relu([r,x]@w1+b1)@w2+b2) ------------
__global__ void k_tpmlp(const float* __restrict__ r_seq, const float* __restrict__ x_wls,
                        const float* __restrict__ w1, const float* __restrict__ b1,
                        const float* __restrict__ w2, const float* __restrict__ b2,
                        float* __restrict__ sout) {
  __shared__ float in_row[kM + 2 * kN];  // 166
  __shared__ float h1[kH];
  const int bw = blockIdx.x, tid = threadIdx.x;
  if (tid < kM) in_row[tid] = r_seq[bw * kM + tid];
  else if (tid < kM + 2 * kN) in_row[tid] = x_wls[bw * 2 * kN + (tid - kM)];
  __syncthreads();
  float a = b1[tid];
  for (int k = 0; k < kM + 2 * kN; ++k) a = fmaf(in_row[k], w1[k * kH + tid], a);
  h1[tid] = fmaxf(a, 0.f);
  __syncthreads();
  float a2 = b2[tid];
  #pragma unroll 4
  for (int k = 0; k < kH; ++k) a2 = fmaf(h1[k], w2[k * kH + tid], a2);
  sout[bw * kH + tid] = fmaxf(a2, 0.f);
}

// ---------------- gi = s @ wih + bih (per (b,w) row, 768 outputs) ----------------
__global__ void k_gigemm(const float* __restrict__ sin, const float* __restrict__ wih,
                         const float* __restrict__ bih, float* __restrict__ gi) {
  __shared__ float srow[kH];
  const int bw = blockIdx.x, tid = threadIdx.x;
  if (tid < kH) srow[tid] = sin[bw * kH + tid];
  __syncthreads();
  float a = bih[tid];
  const float* wp = wih + tid;
  #pragma unroll 8
  for (int k = 0; k < kH; ++k) a = fmaf(srow[k], wp[k * 768], a);
  gi[bw * 768 + tid] = a;
}

// ---------------- GRU scan: one block per batch, h in LDS ------------------------
__global__ void k_scan(const float* __restrict__ gi, const float* __restrict__ whh,
                       const float* __restrict__ bhh, float* __restrict__ sout) {
  __shared__ float h[kH];
  __shared__ float gh[3 * kH];
  const int b = blockIdx.x, tid = threadIdx.x;
  if (tid < kH) h[tid] = 0.f;
  __syncthreads();
  const float* wp = whh + tid;
  for (int t = 0; t < 128; ++t) {
    const float* girow = gi + (b * 128 + t) * 768;
    float a = bhh[tid];
    #pragma unroll 8
    for (int k = 0; k < kH; ++k) a = fmaf(h[k], wp[k * 768], a);
    gh[tid] = a;
    __syncthreads();
    if (tid < kH) {
      float r = sigmoidf(girow[tid] + gh[tid]);
      float z = sigmoidf(girow[kH + tid] + gh[kH + tid]);
      float n = tanhf(fmaf(r, gh[2 * kH + tid], girow[2 * kH + tid]));
      float hn = (1.f - z) * n + z * h[tid];
      h[tid] = hn;
      sout[(b * 128 + t) * kH + tid] = hn;
    }
    __syncthreads();
  }
}

// ---------------- sfuse = s@fs_w+fs_b ; sgate = sfuse@gate_w[256:]+gate_b --------
__global__ void k_fsgate(const float* __restrict__ s1, const float* __restrict__ fsw,
                         const float* __restrict__ fsb, const float* __restrict__ gw,
                         const float* __restrict__ gb, float* __restrict__ sfuse,
                         float* __restrict__ sgate) {
  __shared__ float srow[kH], sf[kH];
  const int bw = blockIdx.x, tid = threadIdx.x;
  srow[tid] = s1[bw * kH + tid];
  __syncthreads();
  float a = fsb[tid];
  #pragma unroll 4
  for (int k = 0; k < kH; ++k) a = fmaf(srow[k], fsw[k * kH + tid], a);
  sf[tid] = a;
  sfuse[bw * kH + tid] = a;
  __syncthreads();
  float a2 = gb[tid];
  #pragma unroll 4
  for (int k = 0; k < kH; ++k) a2 = fmaf(sf[k], gw[(kH + k) * kH + tid], a2);
  sgate[bw * kH + tid] = a2;
}

// ---------------- helpers for the fused GNN kernel -------------------------------
// dst[n*Jd+j] (LDS) (+)= sum_k src[n*Kd+k] * W[k*Jd+j]   (n < 33)
// MODE 0: dst = src@W (+bias)   MODE 1: dst += src@W
template <int Kd, int Jd, int MODE, bool RELU>
DEV void mm33(float* __restrict__ dst, const float* __restrict__ src,
              const float* __restrict__ W, const float* __restrict__ bias) {
  constexpr int JT = Jd / 4;
  constexpr int RP = 256 / JT;
  const int tid = threadIdx.x;
  const int j4 = (tid % JT) * 4;
  const int nh = tid / JT;
  for (int n = nh; n < kN; n += RP) {
    float4 acc;
    if (MODE == 0 && bias != nullptr)
      acc = make_float4(bias[j4], bias[j4 + 1], bias[j4 + 2], bias[j4 + 3]);
    else
      acc = make_float4(0.f, 0.f, 0.f, 0.f);
    const float* srow = src + n * Kd;
    const float* wp = W + j4;
    #pragma unroll 4
    for (int k = 0; k < Kd; ++k) {
      const float s = srow[k];
      const float4 w = *reinterpret_cast<const float4*>(wp + k * Jd);
      acc.x = fmaf(s, w.x, acc.x);
      acc.y = fmaf(s, w.y, acc.y);
      acc.z = fmaf(s, w.z, acc.z);
      acc.w = fmaf(s, w.w, acc.w);
    }
    float* d = dst + n * Jd + j4;
    if (MODE == 1) { acc.x += d[0]; acc.y += d[1]; acc.z += d[2]; acc.w += d[3]; }
    if (RELU) {
      acc.x = fmaxf(acc.x, 0.f); acc.y = fmaxf(acc.y, 0.f);
      acc.z = fmaxf(acc.z, 0.f); acc.w = fmaxf(acc.w, 0.f);
    }
    d[0] = acc.x; d[1] = acc.y; d[2] = acc.z; d[3] = acc.w;
  }
}

// dst = normalized-adjacency @ src  (CSR by dst node, <=3 in-edges per node)
DEV void prop33(float* __restrict__ dst, const float* __restrict__ src,
                const int* __restrict__ rp, const int* __restrict__ cs,
                const float* __restrict__ cn) {
  for (int idx = threadIdx.x; idx < kN * kGH; idx += 256) {
    const int n = idx >> 7, j = idx & 127;
    float a = 0.f;
    const int p1 = rp[n + 1];
    for (int p = rp[n]; p < p1; ++p) a = fmaf(src[cs[p] * kGH + j], cn[p], a);
    dst[idx] = a;
  }
}

// out = h@W0 + P h@W1 + P^2 h@W2 + P^3 h@W3 + b, optional relu; result back in G.
template <bool RELU>
DEV void tag_pass(float* __restrict__ G, float* __restrict__ T,
                  const float* __restrict__ W, const float* __restrict__ b,
                  const int* __restrict__ rp, const int* __restrict__ cs,
                  const float* __restrict__ cn) {
  float* hk = T;
  float* acc = T + kN * kGH;
  mm33<kGH, kGH, 0, false>(acc, G, W, b);
  prop33(hk, G, rp, cs, cn);
  __syncthreads();
  mm33<kGH, kGH, 1, false>(acc, hk, W + kGH * kGH, nullptr);
  prop33(G, hk, rp, cs, cn);           // G <- P^2 h (old G fully consumed)
  __syncthreads();
  mm33<kGH, kGH, 1, false>(acc, G, W + 2 * kGH * kGH, nullptr);
  prop33(hk, G, rp, cs, cn);           // hk <- P^3 h
  __syncthreads();
  mm33<kGH, kGH, 1, false>(acc, hk, W + 3 * kGH * kGH, nullptr);
  __syncthreads();
  for (int idx = threadIdx.x; idx < kN * kGH; idx += 256) {
    const float v = acc[idx];
    G[idx] = RELU ? fmaxf(v, 0.f) : v;
  }
  __syncthreads();
}

// ---------------- fused GNN + gate + decoder, one block per (b,w) ----------------
__global__ __launch_bounds__(256) void k_fused(
    const float* __restrict__ feat_seq, const float* __restrict__ x_wls,
    const float* __restrict__ pre_w, const float* __restrict__ pre_b,
    const float* __restrict__ tw1, const float* __restrict__ tb1,
    const float* __restrict__ tw2, const float* __restrict__ tb2,
    const float* __restrict__ gate_w,
    const float* __restrict__ d1w, const float* __restrict__ d1b,
    const float* __restrict__ d2w, const float* __restrict__ d2b,
    const float* __restrict__ ws,
    const float* __restrict__ sfuse, const float* __restrict__ sgate,
    float* __restrict__ out) {
  __shared__ __align__(16) float S[16896];  // [T:8448][G:4224][D:4224]
  __shared__ float xw[2 * kN];
  __shared__ float sfrow[kH], sgrow[kH];
  __shared__ float featl[kF];
  __shared__ int rp[kN + 1], cs[kE];
  __shared__ float cn[kE];
  float* Treg = S;         // 8448 (hk+acc during tags; later g_t; later v)
  float* Greg = S + 8448;  // 4224 (node features / tag state)
  float* Ureg = S + 8448;  // 8448 contiguous (G+D) — used once Greg is dead
  const int tid = threadIdx.x, bw = blockIdx.x;

  sfrow[tid] = sfuse[bw * kH + tid];
  sgrow[tid] = sgate[bw * kH + tid];
  if (tid < 2 * kN) xw[tid] = x_wls[bw * 2 * kN + tid];
  if (tid < kF) featl[tid] = feat_seq[bw * kF + tid];
  if (tid < kN + 1) rp[tid] = ((const int*)(ws + OFF_ROWPTR))[tid];
  if (tid >= 64 && tid < 128) {
    cs[tid - 64] = ((const int*)(ws + OFF_COLSRC))[tid - 64];
    cn[tid - 64] = ws[OFF_COLNORM + tid - 64];
  }
  __syncthreads();

  // gin = [feat(8), va, vm] @ pre_w + pre_b  -> Greg (33x128)
  for (int idx = tid; idx < kN * kGH; idx += 256) {
    const int n = idx >> 7, j = idx & 127;
    float a = pre_b[j];
    #pragma unroll
    for (int f = 0; f < kF; ++f) a = fmaf(featl[f], pre_w[f * kGH + j], a);
    a = fmaf(xw[n], pre_w[8 * kGH + j], a);
    a = fmaf(xw[kN + n], pre_w[9 * kGH + j], a);
    Greg[idx] = a;
  }
  __syncthreads();

  tag_pass<true>(Greg, Treg, tw1, tb1, rp, cs, cn);
  tag_pass<false>(Greg, Treg, tw2, tb2, rp, cs, cn);

  // g_t = G @ Wc + c  -> Treg (33x256)   [post+fg folded]
  mm33<kGH, kH, 0, false>(Treg, Greg, ws + OFF_WC, ws + OFF_C);
  __syncthreads();

  // alpha = sigmoid(g_t@gate_w[:256] + sgate) ; U = alpha*g_t + (1-alpha)*sfuse
  {
    const int j4 = (tid & 63) * 4;
    const int nh = tid >> 6;
    for (int n = nh; n < kN; n += 4) {
      float4 acc = make_float4(sgrow[j4], sgrow[j4 + 1], sgrow[j4 + 2], sgrow[j4 + 3]);
      const float* srow = Treg + n * kH;
      const float* wp = gate_w + j4;
      #pragma unroll 4
      for (int k = 0; k < kH; ++k) {
        const float s = srow[k];
        const float4 w = *reinterpret_cast<const float4*>(wp + k * kH);
        acc.x = fmaf(s, w.x, acc.x);
        acc.y = fmaf(s, w.y, acc.y);
        acc.z = fmaf(s, w.z, acc.z);
        acc.w = fmaf(s, w.w, acc.w);
      }
      const float4 gt = *reinterpret_cast<const float4*>(Treg + n * kH + j4);
      float4 u;
      float a0 = sigmoidf(acc.x); u.x = a0 * gt.x + (1.f - a0) * sfrow[j4];
      float a1 = sigmoidf(acc.y); u.y = a1 * gt.y + (1.f - a1) * sfrow[j4 + 1];
      float a2 = sigmoidf(acc.z); u.z = a2 * gt.z + (1.f - a2) * sfrow[j4 + 2];
      float a3 = sigmoidf(acc.w); u.w = a3 * gt.w + (1.f - a3) * sfrow[j4 + 3];
      *reinterpret_cast<float4*>(Ureg + n * kH + j4) = u;
    }
  }
  __syncthreads();

  // V = relu(U @ d1w + d1b) -> Treg (g_t dead)
  mm33<kH, kH, 0, true>(Treg, Ureg, d1w, d1b);
  __syncthreads();

  // d2 (256 -> 2) + residual output
  if (tid < kN) {
    float a0 = d2b[0], a1 = d2b[1];
    const float* vr = Treg + tid * kH;
    #pragma unroll 4
    for (int k = 0; k < kH; ++k) {
      const float v = vr[k];
      a0 = fmaf(v, d2w[2 * k], a0);
      a1 = fmaf(v, d2w[2 * k + 1], a1);
    }
    out[bw * 2 * kN + tid] = xw[tid] + a0;
    out[bw * 2 * kN + kN + tid] = xw[kN + tid] + a1;
  }
}

extern "C" void kernel_launch(void* const* d_in, const int* in_sizes, int n_in,
                              void* d_out, int out_size, void* d_ws, size_t ws_size,
                              hipStream_t stream) {
  const float* r_seq  = (const float*)d_in[0];
  const float* feat   = (const float*)d_in[1];
  const float* x_wls  = (const float*)d_in[2];
  const int*   eidx   = (const int*)d_in[3];
  const float* ew     = (const float*)d_in[4];
  const float* pre_w  = (const float*)d_in[5];
  const float* pre_b  = (const float*)d_in[6];
  const float* tag_w1 = (const float*)d_in[7];
  const float* tag_b1 = (const float*)d_in[8];
  const float* tag_w2 = (const float*)d_in[9];
  const float* tag_b2 = (const float*)d_in[10];
  const float* post_w = (const float*)d_in[11];
  const float* post_b = (const float*)d_in[12];
  const float* tp_w1  = (const float*)d_in[13];
  const float* tp_b1  = (const float*)d_in[14];
  const float* tp_w2  = (const float*)d_in[15];
  const float* tp_b2  = (const float*)d_in[16];
  const float* wih0   = (const float*)d_in[17];
  const float* whh0   = (const float*)d_in[18];
  const float* bih0   = (const float*)d_in[19];
  const float* bhh0   = (const float*)d_in[20];
  const float* wih1   = (const float*)d_in[21];
  const float* whh1   = (const float*)d_in[22];
  const float* bih1   = (const float*)d_in[23];
  const float* bhh1   = (const float*)d_in[24];
  const float* fg_w   = (const float*)d_in[25];
  const float* fg_b   = (const float*)d_in[26];
  const float* fs_w   = (const float*)d_in[27];
  const float* fs_b   = (const float*)d_in[28];
  const float* gate_w = (const float*)d_in[29];
  const float* gate_b = (const float*)d_in[30];
  const float* d1_w   = (const float*)d_in[31];
  const float* d1_b   = (const float*)d_in[32];
  const float* d2_w   = (const float*)d_in[33];
  const float* d2_b   = (const float*)d_in[34];
  float* ws = (float*)d_ws;
  float* outp = (float*)d_out;

  k_prep<<<1, 64, 0, stream>>>(eidx, ew, ws);
  k_wcfold<<<kGH + 1, kH, 0, stream>>>(post_w, post_b, fg_w, fg_b, ws);
  k_tpmlp<<<kBW, kH, 0, stream>>>(r_seq, x_wls, tp_w1, tp_b1, tp_w2, tp_b2, ws + OFF_SPRE);
  // GRU layer 0: gi for all t, then scan (s0 overwrites s_pre — it is dead)
  k_gigemm<<<kBW, 768, 0, stream>>>(ws + OFF_SPRE, wih0, bih0, ws + OFF_GI);
  k_scan<<<32, 768, 0, stream>>>(ws + OFF_GI, whh0, bhh0, ws + OFF_SPRE);
  // GRU layer 1
  k_gigemm<<<kBW, 768, 0, stream>>>(ws + OFF_SPRE, wih1, bih1, ws + OFF_GI);
  k_scan<<<32, 768, 0, stream>>>(ws + OFF_GI, whh1, bhh1, ws + OFF_SPRE);
  // s-side fusion precompute
  k_fsgate<<<kBW, kH, 0, stream>>>(ws + OFF_SPRE, fs_w, fs_b, gate_w, gate_b,
                                   ws + OFF_SFUSE, ws + OFF_SGATE);
  // fused GNN + gate + decoder
  k_fused<<<kBW, 256, 0, stream>>>(feat, x_wls, pre_w, pre_b, tag_w1, tag_b1,
                                   tag_w2, tag_b2, gate_w, d1_w, d1_b, d2_w, d2_b,
                                   ws, ws + OFF_SFUSE, ws + OFF_SGATE, outp);
}

// Round 2
// 2675.162 us; speedup vs baseline: 2.5861x; 2.5861x over previous
//
#include <hip/hip_runtime.h>
#include <cmath>

#define DEV __device__ __forceinline__

constexpr int kBW = 4096;          // B*W
constexpr int kM = 100, kF = 8, kN = 33, kH = 256, kGH = 128, kE = 64;

// ws offsets (in floats)
constexpr int OFF_ROWPTR  = 0;       // 34 int
constexpr int OFF_COLSRC  = 64;      // 64 int
constexpr int OFF_COLNORM = 128;     // 64 f
constexpr int OFF_C       = 192;     // 256 f (folded bias)
constexpr int OFF_WC      = 512;     // 128*256 f (post_w@fg_w)
constexpr int OFF_SPRE    = 33280;               // 4096*256 (s_pre -> s0 -> s1)
constexpr int OFF_GI      = OFF_SPRE + kBW * kH; // 4096*768
constexpr int OFF_SFUSE   = OFF_GI + kBW * 3 * kH;
constexpr int OFF_SGATE   = OFF_SFUSE + kBW * kH;
// packed bf16 whh matrices live in the SFUSE region (dead until k_fsgate runs,
// consumed by the scans before k_fsgate writes sfuse):
constexpr int OFF_WPK0    = OFF_SFUSE;           // 128*768 u32
constexpr int OFF_WPK1    = OFF_SFUSE + 98304;   // 128*768 u32

DEV float sigmoidf(float x) { return 1.0f / (1.0f + expf(-x)); }

DEV unsigned short f2bf(float x) {
  unsigned u = __float_as_uint(x);
  unsigned r = u + 0x7fffu + ((u >> 16) & 1u);
  return (unsigned short)(r >> 16);
}

// ---------------- graph prep: degree norm + CSR by dst ---------------------------
__global__ void k_prep(const int* __restrict__ ei, const float* __restrict__ ew,
                       float* __restrict__ ws) {
  if (blockIdx.x != 0 || threadIdx.x != 0) return;
  int* rowptr = (int*)(ws + OFF_ROWPTR);
  int* colsrc = (int*)(ws + OFF_COLSRC);
  float* colnorm = ws + OFF_COLNORM;
  const int* src = ei;
  const int* dst = ei + kE;
  float deg[kN]; int cnt[kN];
  for (int n = 0; n < kN; ++n) { deg[n] = 0.f; cnt[n] = 0; }
  for (int e = 0; e < kE; ++e) { deg[dst[e]] += ew[e]; cnt[dst[e]]++; }
  float dinv[kN];
  for (int n = 0; n < kN; ++n) dinv[n] = deg[n] > 0.f ? 1.0f / sqrtf(deg[n]) : 0.f;
  int pos[kN];
  int run = 0;
  for (int n = 0; n < kN; ++n) { rowptr[n] = run; pos[n] = run; run += cnt[n]; }
  rowptr[kN] = run;
  for (int e = 0; e < kE; ++e) {
    int d = dst[e];
    int p = pos[d]++;
    colsrc[p] = src[e];
    colnorm[p] = dinv[src[e]] * ew[e] * dinv[d];
  }
}

// ---------------- fold Wc = post_w @ fg_w (128x256), c = post_b @ fg_w + fg_b -----
__global__ void k_wcfold(const float* __restrict__ post_w, const float* __restrict__ post_b,
                         const float* __restrict__ fg_w, const float* __restrict__ fg_b,
                         float* __restrict__ ws) {
  const int j = threadIdx.x;
  if ((int)blockIdx.x < kGH) {
    const int k = blockIdx.x;
    float a = 0.f;
    #pragma unroll 4
    for (int m = 0; m < kH; ++m) a = fmaf(post_w[k * kH + m], fg_w[m * kH + j], a);
    ws[OFF_WC + k * kH + j] = a;
  } else {
    float a = fg_b[j];
    #pragma unroll 4
    for (int m = 0; m < kH; ++m) a = fmaf(post_b[m], fg_w[m * kH + j], a);
    ws[OFF_C + j] = a;
  }
}

// ---------------- pack whh (256x768 f32) -> (128x768 u32 of 2xbf16) --------------
__global__ void k_cvt(const float* __restrict__ w0, const float* __restrict__ w1,
                      float* __restrict__ ws) {
  unsigned* p0 = (unsigned*)(ws + OFF_WPK0);
  unsigned* p1 = (unsigned*)(ws + OFF_WPK1);
  const int idx = blockIdx.x * 256 + threadIdx.x;
  if (idx >= 128 * 768) return;
  const int k2 = idx / 768, j = idx - k2 * 768;
  {
    unsigned lo = f2bf(w0[(2 * k2) * 768 + j]);
    unsigned hi = f2bf(w0[(2 * k2 + 1) * 768 + j]);
    p0[idx] = lo | (hi << 16);
  }
  {
    unsigned lo = f2bf(w1[(2 * k2) * 768 + j]);
    unsigned hi = f2bf(w1[(2 * k2 + 1) * 768 + j]);
    p1[idx] = lo | (hi << 16);
  }
}

// ---------------- temporal pre-MLP, 8 rows per block ------------------------------
__global__ __launch_bounds__(256) void k_tpmlp(
    const float* __restrict__ r_seq, const float* __restrict__ x_wls,
    const float* __restrict__ w1, const float* __restrict__ b1,
    const float* __restrict__ w2, const float* __restrict__ b2,
    float* __restrict__ sout) {
  __shared__ float inr[8][kM + 2 * kN];  // 8 x 166
  __shared__ float h1[8][kH];
  const int bw0 = blockIdx.x * 8, tid = threadIdx.x;
  #pragma unroll
  for (int r = 0; r < 8; ++r) {
    for (int c = tid; c < kM + 2 * kN; c += 256)
      inr[r][c] = (c < kM) ? r_seq[(bw0 + r) * kM + c]
                           : x_wls[(bw0 + r) * 2 * kN + (c - kM)];
  }
  __syncthreads();
  float acc[8];
  {
    const float bb = b1[tid];
    #pragma unroll
    for (int r = 0; r < 8; ++r) acc[r] = bb;
  }
  for (int k = 0; k < kM + 2 * kN; ++k) {
    const float w = w1[k * kH + tid];
    #pragma unroll
    for (int r = 0; r < 8; ++r) acc[r] = fmaf(inr[r][k], w, acc[r]);
  }
  #pragma unroll
  for (int r = 0; r < 8; ++r) h1[r][tid] = fmaxf(acc[r], 0.f);
  __syncthreads();
  {
    const float bb = b2[tid];
    #pragma unroll
    for (int r = 0; r < 8; ++r) acc[r] = bb;
  }
  #pragma unroll 2
  for (int k = 0; k < kH; ++k) {
    const float w = w2[k * kH + tid];
    #pragma unroll
    for (int r = 0; r < 8; ++r) acc[r] = fmaf(h1[r][k], w, acc[r]);
  }
  #pragma unroll
  for (int r = 0; r < 8; ++r) sout[(bw0 + r) * kH + tid] = fmaxf(acc[r], 0.f);
}

// ---------------- gi = s @ wih + bih, 8 rows per block ----------------------------
__global__ __launch_bounds__(768) void k_gigemm(
    const float* __restrict__ sin, const float* __restrict__ wih,
    const float* __restrict__ bih, float* __restrict__ gi) {
  __shared__ float sr[8][kH];
  const int bw0 = blockIdx.x * 8, tid = threadIdx.x;
  for (int i = tid; i < 8 * kH; i += 768) sr[i >> 8][i & 255] = sin[bw0 * kH + i];
  __syncthreads();
  float acc[8];
  {
    const float bb = bih[tid];
    #pragma unroll
    for (int r = 0; r < 8; ++r) acc[r] = bb;
  }
  #pragma unroll 2
  for (int k = 0; k < kH; ++k) {
    const float w = wih[k * 768 + tid];
    #pragma unroll
    for (int r = 0; r < 8; ++r) acc[r] = fmaf(sr[r][k], w, acc[r]);
  }
  #pragma unroll
  for (int r = 0; r < 8; ++r) gi[(bw0 + r) * 768 + tid] = acc[r];
}

// ---------------- GRU scan: one block per batch, bf16-packed whh ------------------
__global__ __launch_bounds__(768) void k_scan(
    const float* __restrict__ gi, const float* __restrict__ ws_wpk,
    const float* __restrict__ bhh, float* __restrict__ sout) {
  __shared__ __align__(16) float h[kH];
  __shared__ float gh[3 * kH];
  const int b = blockIdx.x, tid = threadIdx.x;
  if (tid < kH) h[tid] = 0.f;
  __syncthreads();
  const unsigned* wp = (const unsigned*)ws_wpk + tid;
  const float bb = bhh[tid];
  for (int t = 0; t < 128; ++t) {
    const float* girow = gi + (b * 128 + t) * 768;
    float a = bb;
    #pragma unroll 8
    for (int k2 = 0; k2 < 128; ++k2) {
      const unsigned u = wp[k2 * 768];
      const float2 h2 = *reinterpret_cast<const float2*>(h + 2 * k2);
      a = fmaf(__uint_as_float(u << 16), h2.x, a);
      a = fmaf(__uint_as_float(u & 0xffff0000u), h2.y, a);
    }
    gh[tid] = a;
    __syncthreads();
    if (tid < kH) {
      float r = sigmoidf(girow[tid] + gh[tid]);
      float z = sigmoidf(girow[kH + tid] + gh[kH + tid]);
      float n = tanhf(fmaf(r, gh[2 * kH + tid], girow[2 * kH + tid]));
      float hn = (1.f - z) * n + z * h[tid];
      h[tid] = hn;
      sout[(b * 128 + t) * kH + tid] = hn;
    }
    __syncthreads();
  }
}

// ---------------- sfuse/sgate, 8 rows per block -----------------------------------
__global__ __launch_bounds__(256) void k_fsgate(
    const float* __restrict__ s1, const float* __restrict__ fsw,
    const float* __restrict__ fsb, const float* __restrict__ gw,
    const float* __restrict__ gb, float* __restrict__ sfuse,
    float* __restrict__ sgate) {
  __shared__ float sr[8][kH], sf[8][kH];
  const int bw0 = blockIdx.x * 8, tid = threadIdx.x;
  for (int i = tid; i < 8 * kH; i += 256) sr[i >> 8][i & 255] = s1[bw0 * kH + i];
  __syncthreads();
  float acc[8];
  {
    const float bb = fsb[tid];
    #pragma unroll
    for (int r = 0; r < 8; ++r) acc[r] = bb;
  }
  #pragma unroll 2
  for (int k = 0; k < kH; ++k) {
    const float w = fsw[k * kH + tid];
    #pragma unroll
    for (int r = 0; r < 8; ++r) acc[r] = fmaf(sr[r][k], w, acc[r]);
  }
  #pragma unroll
  for (int r = 0; r < 8; ++r) { sf[r][tid] = acc[r]; sfuse[(bw0 + r) * kH + tid] = acc[r]; }
  __syncthreads();
  {
    const float bb = gb[tid];
    #pragma unroll
    for (int r = 0; r < 8; ++r) acc[r] = bb;
  }
  #pragma unroll 2
  for (int k = 0; k < kH; ++k) {
    const float w = gw[(kH + k) * kH + tid];
    #pragma unroll
    for (int r = 0; r < 8; ++r) acc[r] = fmaf(sf[r][k], w, acc[r]);
  }
  #pragma unroll
  for (int r = 0; r < 8; ++r) sgate[(bw0 + r) * kH + tid] = acc[r];
}

// ================= fused GNN + gate + decoder =====================================
// 256 threads = 4 waves. Rows padded to 36. Wave w owns rows {w + 4t, t=0..8}.
// Tag matmuls: k-split across wave halves (lane>=32 handles k in [64,128)),
// combined with shfl_xor(32). Weights loaded once per k, reused for 9 rows.

constexpr int NR = 36;  // padded row count

// dst = normalized-adjacency @ src, rows 0..32 (pad rows untouched)
DEV void prop33(float* __restrict__ dst, const float* __restrict__ src,
                const int* __restrict__ rp, const int* __restrict__ cs,
                const float* __restrict__ cn) {
  for (int idx = threadIdx.x; idx < kN * kGH; idx += 256) {
    const int n = idx >> 7, j = idx & 127;
    float a = 0.f;
    const int p1 = rp[n + 1];
    for (int p = rp[n]; p < p1; ++p) a = fmaf(src[cs[p] * kGH + j], cn[p], a);
    dst[idx] = a;
  }
}

// acc[t] += X[rows][k-half] @ W (Jd=128), k-split by wave half
DEV void mmacc128(float4* __restrict__ acc, const float* __restrict__ X,
                  const float* __restrict__ W, int k0, int j4, int wv) {
  const float* wp = W + j4;
  #pragma unroll 2
  for (int k = k0; k < k0 + 64; ++k) {
    const float4 w4 = *reinterpret_cast<const float4*>(wp + k * kGH);
    #pragma unroll
    for (int t = 0; t < 9; ++t) {
      const float s = X[(wv + 4 * t) * kGH + k];
      acc[t].x = fmaf(s, w4.x, acc[t].x);
      acc[t].y = fmaf(s, w4.y, acc[t].y);
      acc[t].z = fmaf(s, w4.z, acc[t].z);
      acc[t].w = fmaf(s, w4.w, acc[t].w);
    }
  }
}

template <bool RELU>
DEV void tag_pass(float* __restrict__ A, float* __restrict__ B,
                  const float* __restrict__ W, const float* __restrict__ b,
                  const int* __restrict__ rp, const int* __restrict__ cs,
                  const float* __restrict__ cn, int wv, int lane) {
  const int half = lane >> 5;
  const int j4 = (lane & 31) * 4;
  const int k0 = half * 64;
  float4 acc[9];
  #pragma unroll
  for (int t = 0; t < 9; ++t) acc[t] = make_float4(0.f, 0.f, 0.f, 0.f);

  mmacc128(acc, A, W,                 k0, j4, wv);   // h @ W0
  prop33(B, A, rp, cs, cn);                          // B = P h
  __syncthreads();
  mmacc128(acc, B, W + kGH * kGH,     k0, j4, wv);   // + Ph @ W1
  prop33(A, B, rp, cs, cn);                          // A = P^2 h
  __syncthreads();
  mmacc128(acc, A, W + 2 * kGH * kGH, k0, j4, wv);   // + P^2 h @ W2
  prop33(B, A, rp, cs, cn);                          // B = P^3 h
  __syncthreads();
  mmacc128(acc, B, W + 3 * kGH * kGH, k0, j4, wv);   // + P^3 h @ W3

  const float b0 = b[j4], b1 = b[j4 + 1], b2 = b[j4 + 2], b3 = b[j4 + 3];
  #pragma unroll
  for (int t = 0; t < 9; ++t) {
    float ox = acc[t].x + __shfl_xor(acc[t].x, 32, 64);
    float oy = acc[t].y + __shfl_xor(acc[t].y, 32, 64);
    float oz = acc[t].z + __shfl_xor(acc[t].z, 32, 64);
    float ow = acc[t].w + __shfl_xor(acc[t].w, 32, 64);
    if (half == 0) {
      ox += b0; oy += b1; oz += b2; ow += b3;
      if (RELU) {
        ox = fmaxf(ox, 0.f); oy = fmaxf(oy, 0.f);
        oz = fmaxf(oz, 0.f); ow = fmaxf(ow, 0.f);
      }
      *reinterpret_cast<float4*>(A + (wv + 4 * t) * kGH + j4) =
          make_float4(ox, oy, oz, ow);
    }
  }
  __syncthreads();
}

__global__ __launch_bounds__(256, 4) void k_fused(
    const float* __restrict__ feat_seq, const float* __restrict__ x_wls,
    const float* __restrict__ pre_w, const float* __restrict__ pre_b,
    const float* __restrict__ tw1, const float* __restrict__ tb1,
    const float* __restrict__ tw2, const float* __restrict__ tb2,
    const float* __restrict__ gate_w,
    const float* __restrict__ d1w, const float* __restrict__ d1b,
    const float* __restrict__ d2w, const float* __restrict__ d2b,
    const float* __restrict__ ws,
    const float* __restrict__ sfuse, const float* __restrict__ sgate,
    float* __restrict__ out) {
  __shared__ __align__(16) float S[2 * NR * kGH];  // 9216 f: A|B, reused as GT(36x256)
  __shared__ __align__(16) float sfrow[kH], sgrow[kH];
  __shared__ float xw[2 * kN];
  __shared__ float featl[kF];
  __shared__ int rp[kN + 1], cs[kE];
  __shared__ float cn[kE];
  float* A = S;
  float* B = S + NR * kGH;
  const int tid = threadIdx.x, bw = blockIdx.x;
  const int wv = tid >> 6;
  const int lane = tid & 63;

  sfrow[tid] = sfuse[bw * kH + tid];
  sgrow[tid] = sgate[bw * kH + tid];
  if (tid < 2 * kN) xw[tid] = x_wls[bw * 2 * kN + tid];
  else if (tid >= 66 && tid < 66 + kF) featl[tid - 66] = feat_seq[bw * kF + (tid - 66)];
  if (tid >= 128 && tid < 128 + kN + 1) rp[tid - 128] = ((const int*)(ws + OFF_ROWPTR))[tid - 128];
  if (tid >= 192) {
    cs[tid - 192] = ((const int*)(ws + OFF_COLSRC))[tid - 192];
    cn[tid - 192] = ws[OFF_COLNORM + (tid - 192)];
  }
  // zero pad rows 33..35 of A and B
  for (int i = tid; i < (NR - kN) * kGH; i += 256) {
    A[kN * kGH + i] = 0.f;
    B[kN * kGH + i] = 0.f;
  }
  __syncthreads();

  // gin = [feat(8), va, vm] @ pre_w + pre_b  -> A rows 0..32
  for (int idx = tid; idx < kN * kGH; idx += 256) {
    const int n = idx >> 7, j = idx & 127;
    float a = pre_b[j];
    #pragma unroll
    for (int f = 0; f < kF; ++f) a = fmaf(featl[f], pre_w[f * kGH + j], a);
    a = fmaf(xw[n], pre_w[8 * kGH + j], a);
    a = fmaf(xw[kN + n], pre_w[9 * kGH + j], a);
    A[idx] = a;
  }
  __syncthreads();

  tag_pass<true >(A, B, tw1, tb1, rp, cs, cn, wv, lane);
  tag_pass<false>(A, B, tw2, tb2, rp, cs, cn, wv, lane);

  // ---- g_t = A @ Wc + c  (rows per wave, acc in regs) ----
  {
    const int j4 = lane * 4;
    const float* Wc = ws + OFF_WC;
    float4 acc[9];
    const float4 cb = *reinterpret_cast<const float4*>(ws + OFF_C + j4);
    #pragma unroll
    for (int t = 0; t < 9; ++t) acc[t] = cb;
    #pragma unroll 2
    for (int k = 0; k < kGH; ++k) {
      const float4 w4 = *reinterpret_cast<const float4*>(Wc + k * kH + j4);
      #pragma unroll
      for (int t = 0; t < 9; ++t) {
        const float s = A[(wv + 4 * t) * kGH + k];
        acc[t].x = fmaf(s, w4.x, acc[t].x);
        acc[t].y = fmaf(s, w4.y, acc[t].y);
        acc[t].z = fmaf(s, w4.z, acc[t].z);
        acc[t].w = fmaf(s, w4.w, acc[t].w);
      }
    }
    __syncthreads();  // all reads of A done; S becomes GT (36x256)
    #pragma unroll
    for (int t = 0; t < 9; ++t)
      *reinterpret_cast<float4*>(S + (wv + 4 * t) * kH + j4) = acc[t];
    // no block sync needed: each wave only touches its own GT rows below
  }

  // ---- gate -> U (overwrites own GT rows), d1 -> V (regs), d2 + residual ----
  {
    const int j4 = lane * 4;
    float4 acc[9];
    const float4 sg = *reinterpret_cast<const float4*>(sfrow + 0 ? sfrow : sgrow + j4);
    // (avoid accidental misuse; real init below)
    #pragma unroll
    for (int t = 0; t < 9; ++t) acc[t] = *reinterpret_cast<const float4*>(sgrow + j4);
    #pragma unroll 2
    for (int k = 0; k < kH; ++k) {
      const float4 w4 = *reinterpret_cast<const float4*>(gate_w + k * kH + j4);
      #pragma unroll
      for (int t = 0; t < 9; ++t) {
        const float s = S[(wv + 4 * t) * kH + k];
        acc[t].x = fmaf(s, w4.x, acc[t].x);
        acc[t].y = fmaf(s, w4.y, acc[t].y);
        acc[t].z = fmaf(s, w4.z, acc[t].z);
        acc[t].w = fmaf(s, w4.w, acc[t].w);
      }
    }
    const float4 sf4 = *reinterpret_cast<const float4*>(sfrow + j4);
    #pragma unroll
    for (int t = 0; t < 9; ++t) {
      float4* gtp = reinterpret_cast<float4*>(S + (wv + 4 * t) * kH + j4);
      const float4 gt = *gtp;
      float a0 = sigmoidf(acc[t].x);
      float a1 = sigmoidf(acc[t].y);
      float a2 = sigmoidf(acc[t].z);
      float a3 = sigmoidf(acc[t].w);
      float4 u;
      u.x = a0 * gt.x + (1.f - a0) * sf4.x;
      u.y = a1 * gt.y + (1.f - a1) * sf4.y;
      u.z = a2 * gt.z + (1.f - a2) * sf4.z;
      u.w = a3 * gt.w + (1.f - a3) * sf4.w;
      *gtp = u;  // wave-lockstep: all lanes finished reading row before writes
    }
    (void)sg;

    // d1: V = relu(U @ d1w + d1b)
    {
      const float4 db = *reinterpret_cast<const float4*>(d1b + j4);
      #pragma unroll
      for (int t = 0; t < 9; ++t) acc[t] = db;
    }
    #pragma unroll 2
    for (int k = 0; k < kH; ++k) {
      const float4 w4 = *reinterpret_cast<const float4*>(d1w + k * kH + j4);
      #pragma unroll
      for (int t = 0; t < 9; ++t) {
        const float s = S[(wv + 4 * t) * kH + k];
        acc[t].x = fmaf(s, w4.x, acc[t].x);
        acc[t].y = fmaf(s, w4.y, acc[t].y);
        acc[t].z = fmaf(s, w4.z, acc[t].z);
        acc[t].w = fmaf(s, w4.w, acc[t].w);
      }
    }
    // d2 (256 -> 2) with wave reduction + residual
    float2 d2r[4];
    #pragma unroll
    for (int i = 0; i < 4; ++i)
      d2r[i] = *reinterpret_cast<const float2*>(d2w + (j4 + i) * 2);
    const float d2b0 = d2b[0], d2b1 = d2b[1];
    #pragma unroll
    for (int t = 0; t < 9; ++t) {
      const int r = wv + 4 * t;
      float vx = fmaxf(acc[t].x, 0.f), vy = fmaxf(acc[t].y, 0.f);
      float vz = fmaxf(acc[t].z, 0.f), vw = fmaxf(acc[t].w, 0.f);
      float p0 = vx * d2r[0].x + vy * d2r[1].x + vz * d2r[2].x + vw * d2r[3].x;
      float p1 = vx * d2r[0].y + vy * d2r[1].y + vz * d2r[2].y + vw * d2r[3].y;
      #pragma unroll
      for (int off = 32; off > 0; off >>= 1) {
        p0 += __shfl_xor(p0, off, 64);
        p1 += __shfl_xor(p1, off, 64);
      }
      if (lane == 0 && r < kN) {
        out[bw * 2 * kN + r] = xw[r] + p0 + d2b0;
        out[bw * 2 * kN + kN + r] = xw[kN + r] + p1 + d2b1;
      }
    }
  }
}

extern "C" void kernel_launch(void* const* d_in, const int* in_sizes, int n_in,
                              void* d_out, int out_size, void* d_ws, size_t ws_size,
                              hipStream_t stream) {
  const float* r_seq  = (const float*)d_in[0];
  const float* feat   = (const float*)d_in[1];
  const float* x_wls  = (const float*)d_in[2];
  const int*   eidx   = (const int*)d_in[3];
  const float* ew     = (const float*)d_in[4];
  const float* pre_w  = (const float*)d_in[5];
  const float* pre_b  = (const float*)d_in[6];
  const float* tag_w1 = (const float*)d_in[7];
  const float* tag_b1 = (const float*)d_in[8];
  const float* tag_w2 = (const float*)d_in[9];
  const float* tag_b2 = (const float*)d_in[10];
  const float* post_w = (const float*)d_in[11];
  const float* post_b = (const float*)d_in[12];
  const float* tp_w1  = (const float*)d_in[13];
  const float* tp_b1  = (const float*)d_in[14];
  const float* tp_w2  = (const float*)d_in[15];
  const float* tp_b2  = (const float*)d_in[16];
  const float* wih0   = (const float*)d_in[17];
  const float* whh0   = (const float*)d_in[18];
  const float* bih0   = (const float*)d_in[19];
  const float* bhh0   = (const float*)d_in[20];
  const float* wih1   = (const float*)d_in[21];
  const float* whh1   = (const float*)d_in[22];
  const float* bih1   = (const float*)d_in[23];
  const float* bhh1   = (const float*)d_in[24];
  const float* fg_w   = (const float*)d_in[25];
  const float* fg_b   = (const float*)d_in[26];
  const float* fs_w   = (const float*)d_in[27];
  const float* fs_b   = (const float*)d_in[28];
  const float* gate_w = (const float*)d_in[29];
  const float* gate_b = (const float*)d_in[30];
  const float* d1_w   = (const float*)d_in[31];
  const float* d1_b   = (const float*)d_in[32];
  const float* d2_w   = (const float*)d_in[33];
  const float* d2_b   = (const float*)d_in[34];
  float* ws = (float*)d_ws;
  float* outp = (float*)d_out;

  k_prep<<<1, 64, 0, stream>>>(eidx, ew, ws);
  k_wcfold<<<kGH + 1, kH, 0, stream>>>(post_w, post_b, fg_w, fg_b, ws);
  k_cvt<<<384, 256, 0, stream>>>(whh0, whh1, ws);
  k_tpmlp<<<kBW / 8, 256, 0, stream>>>(r_seq, x_wls, tp_w1, tp_b1, tp_w2, tp_b2,
                                       ws + OFF_SPRE);
  k_gigemm<<<kBW / 8, 768, 0, stream>>>(ws + OFF_SPRE, wih0, bih0, ws + OFF_GI);
  k_scan<<<32, 768, 0, stream>>>(ws + OFF_GI, ws + OFF_WPK0, bhh0, ws + OFF_SPRE);
  k_gigemm<<<kBW / 8, 768, 0, stream>>>(ws + OFF_SPRE, wih1, bih1, ws + OFF_GI);
  k_scan<<<32, 768, 0, stream>>>(ws + OFF_GI, ws + OFF_WPK1, bhh1, ws + OFF_SPRE);
  k_fsgate<<<kBW / 8, 256, 0, stream>>>(ws + OFF_SPRE, fs_w, fs_b, gate_w, gate_b,
                                        ws + OFF_SFUSE, ws + OFF_SGATE);
  k_fused<<<kBW, 256, 0, stream>>>(feat, x_wls, pre_w, pre_b, tag_w1, tag_b1,
                                   tag_w2, tag_b2, gate_w, d1_w, d1_b, d2_w, d2_b,
                                   ws, ws + OFF_SFUSE, ws + OFF_SGATE, outp);
}

// Round 3
// 2192.127 us; speedup vs baseline: 3.1559x; 1.2203x over previous
//
#include <hip/hip_runtime.h>
#include <cmath>

#define DEV __device__ __forceinline__

typedef unsigned short ushortT;
typedef short bs8 __attribute__((ext_vector_type(8)));
typedef float f32x4 __attribute__((ext_vector_type(4)));

constexpr int kBW = 4096;          // B*W
constexpr int kM = 100, kF = 8, kN = 33, kH = 256, kGH = 128, kE = 64;

// ws offsets (in floats)
constexpr int OFF_ROWPTR  = 0;       // 34 int
constexpr int OFF_COLSRC  = 64;      // 64 int
constexpr int OFF_COLNORM = 128;     // 64 f
constexpr int OFF_C       = 192;     // 256 f (folded bias)
constexpr int OFF_WC      = 512;     // 128*256 f (post_w@fg_w)
constexpr int OFF_SPRE    = 33280;               // 4096*256 (s_pre -> s0 -> s1)
constexpr int OFF_GI      = OFF_SPRE + kBW * kH; // 4096*768 f
constexpr int OFF_SFUSE   = OFF_GI + kBW * 3 * kH;  // 4096*256 f
constexpr int OFF_SGATE   = OFF_SFUSE + kBW * kH;   // 4096*256 f
// scan weights (interleaved f32 [k/4][j][4]) live in SFUSE region (dead until
// k_fsgate, which runs after both scans):
constexpr int OFF_WQ0     = OFF_SFUSE;            // 196608 f
constexpr int OFF_WQ1     = OFF_SFUSE + 196608;   // 196608 f
// bf16 B-fragment weights for k_fused live in GI region (dead after scans):
// ushort offsets within (ushort*)(ws + OFF_GI):
constexpr int WB_TW1  = 0;        // 4*128*128
constexpr int WB_TW2  = 65536;    // 4*128*128
constexpr int WB_WC   = 131072;   // 256 cols x 128 k
constexpr int WB_GATE = 163840;   // 256 cols x 256 k
constexpr int WB_D1   = 229376;   // 256 cols x 256 k
constexpr int WB_TOT  = 294912;

DEV float sigmoidf(float x) { return 1.0f / (1.0f + expf(-x)); }

DEV ushortT f2bf(float x) {
  unsigned u = __float_as_uint(x);
  unsigned r = u + 0x7fffu + ((u >> 16) & 1u);
  return (ushortT)(r >> 16);
}
DEV float bf2f(ushortT u) { return __uint_as_float(((unsigned)u) << 16); }

DEV f32x4 mfma16(bs8 a, bs8 b, f32x4 c) {
  return __builtin_amdgcn_mfma_f32_16x16x32_bf16(a, b, c, 0, 0, 0);
}
DEV bs8 ldb(const ushortT* p) { return *reinterpret_cast<const bs8*>(p); }

// ---------------- graph prep: degree norm + CSR by dst ---------------------------
__global__ void k_prep(const int* __restrict__ ei, const float* __restrict__ ew,
                       float* __restrict__ ws) {
  if (blockIdx.x != 0 || threadIdx.x != 0) return;
  int* rowptr = (int*)(ws + OFF_ROWPTR);
  int* colsrc = (int*)(ws + OFF_COLSRC);
  float* colnorm = ws + OFF_COLNORM;
  const int* src = ei;
  const int* dst = ei + kE;
  float deg[kN]; int cnt[kN];
  for (int n = 0; n < kN; ++n) { deg[n] = 0.f; cnt[n] = 0; }
  for (int e = 0; e < kE; ++e) { deg[dst[e]] += ew[e]; cnt[dst[e]]++; }
  float dinv[kN];
  for (int n = 0; n < kN; ++n) dinv[n] = deg[n] > 0.f ? 1.0f / sqrtf(deg[n]) : 0.f;
  int pos[kN];
  int run = 0;
  for (int n = 0; n < kN; ++n) { rowptr[n] = run; pos[n] = run; run += cnt[n]; }
  rowptr[kN] = run;
  for (int e = 0; e < kE; ++e) {
    int d = dst[e];
    int p = pos[d]++;
    colsrc[p] = src[e];
    colnorm[p] = dinv[src[e]] * ew[e] * dinv[d];
  }
}

// ---------------- fold Wc = post_w @ fg_w (128x256), c = post_b @ fg_w + fg_b -----
__global__ void k_wcfold(const float* __restrict__ post_w, const float* __restrict__ post_b,
                         const float* __restrict__ fg_w, const float* __restrict__ fg_b,
                         float* __restrict__ ws) {
  const int j = threadIdx.x;
  if ((int)blockIdx.x < kGH) {
    const int k = blockIdx.x;
    float a = 0.f;
    #pragma unroll 4
    for (int m = 0; m < kH; ++m) a = fmaf(post_w[k * kH + m], fg_w[m * kH + j], a);
    ws[OFF_WC + k * kH + j] = a;
  } else {
    float a = fg_b[j];
    #pragma unroll 4
    for (int m = 0; m < kH; ++m) a = fmaf(post_b[m], fg_w[m * kH + j], a);
    ws[OFF_C + j] = a;
  }
}

// ---------------- scan weights: whh[k][j] -> wq[(k/4)*768 + j][k%4] f32 -----------
__global__ void k_wq(const float* __restrict__ w0, const float* __restrict__ w1,
                     float* __restrict__ ws) {
  const int idx = blockIdx.x * 256 + threadIdx.x;
  if (idx >= 2 * 196608) return;
  const int layer = idx / 196608;
  const int rem = idx - layer * 196608;
  const int k = rem / 768, j = rem - (rem / 768) * 768;
  const float* w = layer ? w1 : w0;
  float* dst = ws + (layer ? OFF_WQ1 : OFF_WQ0);
  dst[((k >> 2) * 768 + j) * 4 + (k & 3)] = w[k * 768 + j];
}

// ---------------- bf16 B-fragment weights ([col][k]) for k_fused -----------------
__global__ void k_wprep(const float* __restrict__ tw1, const float* __restrict__ tw2,
                        const float* __restrict__ gatew, const float* __restrict__ d1w,
                        float* __restrict__ ws) {
  const int idx = blockIdx.x * 256 + threadIdx.x;
  if (idx >= WB_TOT) return;
  ushortT* WB = (ushortT*)(ws + OFF_GI);
  float v; int dst;
  if (idx < 65536) {
    int s = idx >> 14, r = idx & 16383, k = r >> 7, col = r & 127;
    v = tw1[(s << 14) + (k << 7) + col]; dst = WB_TW1 + (s << 14) + (col << 7) + k;
  } else if (idx < 131072) {
    int i = idx - 65536; int s = i >> 14, r = i & 16383, k = r >> 7, col = r & 127;
    v = tw2[(s << 14) + (k << 7) + col]; dst = WB_TW2 + (s << 14) + (col << 7) + k;
  } else if (idx < 163840) {
    int i = idx - 131072; int k = i & 127, col = i >> 7;
    v = ws[OFF_WC + (k << 8) + col]; dst = WB_WC + (col << 7) + k;
  } else if (idx < 229376) {
    int i = idx - 163840; int k = i & 255, col = i >> 8;
    v = gatew[(k << 8) + col]; dst = WB_GATE + (col << 8) + k;
  } else {
    int i = idx - 229376; int k = i & 255, col = i >> 8;
    v = d1w[(k << 8) + col]; dst = WB_D1 + (col << 8) + k;
  }
  WB[dst] = f2bf(v);
}

// ---------------- temporal pre-MLP, 8 rows per block ------------------------------
__global__ __launch_bounds__(256) void k_tpmlp(
    const float* __restrict__ r_seq, const float* __restrict__ x_wls,
    const float* __restrict__ w1, const float* __restrict__ b1,
    const float* __restrict__ w2, const float* __restrict__ b2,
    float* __restrict__ sout) {
  __shared__ float inr[8][kM + 2 * kN];  // 8 x 166
  __shared__ float h1[8][kH];
  const int bw0 = blockIdx.x * 8, tid = threadIdx.x;
  #pragma unroll
  for (int r = 0; r < 8; ++r) {
    for (int c = tid; c < kM + 2 * kN; c += 256)
      inr[r][c] = (c < kM) ? r_seq[(bw0 + r) * kM + c]
                           : x_wls[(bw0 + r) * 2 * kN + (c - kM)];
  }
  __syncthreads();
  float acc[8];
  {
    const float bb = b1[tid];
    #pragma unroll
    for (int r = 0; r < 8; ++r) acc[r] = bb;
  }
  for (int k = 0; k < kM + 2 * kN; ++k) {
    const float w = w1[k * kH + tid];
    #pragma unroll
    for (int r = 0; r < 8; ++r) acc[r] = fmaf(inr[r][k], w, acc[r]);
  }
  #pragma unroll
  for (int r = 0; r < 8; ++r) h1[r][tid] = fmaxf(acc[r], 0.f);
  __syncthreads();
  {
    const float bb = b2[tid];
    #pragma unroll
    for (int r = 0; r < 8; ++r) acc[r] = bb;
  }
  #pragma unroll 2
  for (int k = 0; k < kH; ++k) {
    const float w = w2[k * kH + tid];
    #pragma unroll
    for (int r = 0; r < 8; ++r) acc[r] = fmaf(h1[r][k], w, acc[r]);
  }
  #pragma unroll
  for (int r = 0; r < 8; ++r) sout[(bw0 + r) * kH + tid] = fmaxf(acc[r], 0.f);
}

// ---------------- gi = s @ wih + bih, 8 rows per block ----------------------------
__global__ __launch_bounds__(768) void k_gigemm(
    const float* __restrict__ sin, const float* __restrict__ wih,
    const float* __restrict__ bih, float* __restrict__ gi) {
  __shared__ float sr[8][kH];
  const int bw0 = blockIdx.x * 8, tid = threadIdx.x;
  for (int i = tid; i < 8 * kH; i += 768) sr[i >> 8][i & 255] = sin[bw0 * kH + i];
  __syncthreads();
  float acc[8];
  {
    const float bb = bih[tid];
    #pragma unroll
    for (int r = 0; r < 8; ++r) acc[r] = bb;
  }
  #pragma unroll 2
  for (int k = 0; k < kH; ++k) {
    const float w = wih[k * 768 + tid];
    #pragma unroll
    for (int r = 0; r < 8; ++r) acc[r] = fmaf(sr[r][k], w, acc[r]);
  }
  #pragma unroll
  for (int r = 0; r < 8; ++r) gi[(bw0 + r) * 768 + tid] = acc[r];
}

// ---------------- GRU scan: one block per batch, interleaved f32 weights ----------
__global__ __launch_bounds__(768) void k_scan(
    const float* __restrict__ gi, const float* __restrict__ wq,
    const float* __restrict__ bhh, float* __restrict__ sout) {
  __shared__ __align__(16) float h[kH];
  __shared__ float gh[3 * kH];
  const int b = blockIdx.x, tid = threadIdx.x;
  if (tid < kH) h[tid] = 0.f;
  __syncthreads();
  const float4* wqp = (const float4*)wq;
  const float bb = bhh[tid];
  for (int t = 0; t < 128; ++t) {
    const float* girow = gi + (b * 128 + t) * 768;
    float a0 = bb, a1 = 0.f;
    #pragma unroll 8
    for (int kb = 0; kb < 64; ++kb) {
      const float4 w = wqp[kb * 768 + tid];
      const float4 h4 = *reinterpret_cast<const float4*>(h + 4 * kb);
      a0 = fmaf(w.x, h4.x, a0);
      a1 = fmaf(w.y, h4.y, a1);
      a0 = fmaf(w.z, h4.z, a0);
      a1 = fmaf(w.w, h4.w, a1);
    }
    gh[tid] = a0 + a1;
    __syncthreads();
    if (tid < kH) {
      float r = sigmoidf(girow[tid] + gh[tid]);
      float z = sigmoidf(girow[kH + tid] + gh[kH + tid]);
      float n = tanhf(fmaf(r, gh[2 * kH + tid], girow[2 * kH + tid]));
      float hn = (1.f - z) * n + z * h[tid];
      h[tid] = hn;
      sout[(b * 128 + t) * kH + tid] = hn;
    }
    __syncthreads();
  }
}

// ---------------- sfuse/sgate, 8 rows per block -----------------------------------
__global__ __launch_bounds__(256) void k_fsgate(
    const float* __restrict__ s1, const float* __restrict__ fsw,
    const float* __restrict__ fsb, const float* __restrict__ gw,
    const float* __restrict__ gb, float* __restrict__ sfuse,
    float* __restrict__ sgate) {
  __shared__ float sr[8][kH], sf[8][kH];
  const int bw0 = blockIdx.x * 8, tid = threadIdx.x;
  for (int i = tid; i < 8 * kH; i += 256) sr[i >> 8][i & 255] = s1[bw0 * kH + i];
  __syncthreads();
  float acc[8];
  {
    const float bb = fsb[tid];
    #pragma unroll
    for (int r = 0; r < 8; ++r) acc[r] = bb;
  }
  #pragma unroll 2
  for (int k = 0; k < kH; ++k) {
    const float w = fsw[k * kH + tid];
    #pragma unroll
    for (int r = 0; r < 8; ++r) acc[r] = fmaf(sr[r][k], w, acc[r]);
  }
  #pragma unroll
  for (int r = 0; r < 8; ++r) { sf[r][tid] = acc[r]; sfuse[(bw0 + r) * kH + tid] = acc[r]; }
  __syncthreads();
  {
    const float bb = gb[tid];
    #pragma unroll
    for (int r = 0; r < 8; ++r) acc[r] = bb;
  }
  #pragma unroll 2
  for (int k = 0; k < kH; ++k) {
    const float w = gw[(kH + k) * kH + tid];
    #pragma unroll
    for (int r = 0; r < 8; ++r) acc[r] = fmaf(sf[r][k], w, acc[r]);
  }
  #pragma unroll
  for (int r = 0; r < 8; ++r) sgate[(bw0 + r) * kH + tid] = acc[r];
}

// ================= fused GNN + gate + decoder (MFMA bf16) =========================
// 256 threads = 4 waves. Activations bf16 in LDS:
//   buf0/buf1: 36 rows x 136 (K=128, +8 pad); GT: rows x 264 (K=256, +8 pad).
// A-frag: row = mt*16 + (lane&15), k = kstep*32 + (lane>>4)*8 (ds_read_b128).
// B-frag: [col][k] bf16 in global (L2); col = ntile*16 + (lane&15).
// C/D: col = lane&15 (+16*nt), row = mt*16 + (lane>>4)*4 + reg.
// M=33 -> 3 M-tiles; rows 33..47 are garbage (reads may spill into the next LDS
// region -> finite-or-NaN, confined to discarded C rows).

constexpr int SB0 = 0;
constexpr int SB1 = 36 * 136;           // 4896
constexpr int SGT = 2 * 36 * 136;       // 9792
constexpr int S_TOT = SGT + 48 * 264;   // 22464 ushorts = 44928 B

// dst(rows<33) = P @ src, bf16 pairs
DEV void propb(ushortT* __restrict__ dst, const ushortT* __restrict__ src,
               const int* __restrict__ rp, const int* __restrict__ cs,
               const float* __restrict__ cn) {
  for (int idx = threadIdx.x; idx < kN * 64; idx += 256) {
    const int n = idx >> 6, j2 = idx & 63;
    float a0 = 0.f, a1 = 0.f;
    const int p1 = rp[n + 1];
    for (int p = rp[n]; p < p1; ++p) {
      const unsigned v = *(const unsigned*)(src + cs[p] * 136 + 2 * j2);
      const float w = cn[p];
      a0 = fmaf(__uint_as_float(v << 16), w, a0);
      a1 = fmaf(__uint_as_float(v & 0xffff0000u), w, a1);
    }
    *(unsigned*)(dst + n * 136 + 2 * j2) = (unsigned)f2bf(a0) | ((unsigned)f2bf(a1) << 16);
  }
}

// tag pass: buf0(h) -> buf0(out), using buf1 as scratch. W stacked 4x[col][k].
template <bool RELU>
DEV void tag_mfma(ushortT* __restrict__ Sb, const ushortT* __restrict__ WT,
                  const float* __restrict__ b, const int* __restrict__ rp,
                  const int* __restrict__ cs, const float* __restrict__ cn,
                  int wv, int lane) {
  const int lr = lane & 15, lg = lane >> 4;
  f32x4 acc[6];
  #pragma unroll
  for (int i = 0; i < 6; ++i) acc[i] = (f32x4){0.f, 0.f, 0.f, 0.f};
  ushortT* bufs[2] = {Sb + SB0, Sb + SB1};
  int cur = 0;
  #pragma unroll
  for (int s = 0; s < 4; ++s) {
    const ushortT* A = bufs[cur];
    #pragma unroll
    for (int ks = 0; ks < 4; ++ks) {
      const int kof = ks * 32 + lg * 8;
      bs8 a0 = ldb(A + (lr) * 136 + kof);
      bs8 a1 = ldb(A + (16 + lr) * 136 + kof);
      bs8 a2 = ldb(A + (32 + lr) * 136 + kof);
      #pragma unroll
      for (int nt = 0; nt < 2; ++nt) {
        const int col = (wv * 2 + nt) * 16 + lr;
        bs8 bb = ldb(WT + (s << 14) + (col << 7) + kof);
        acc[0 + nt] = mfma16(a0, bb, acc[0 + nt]);
        acc[2 + nt] = mfma16(a1, bb, acc[2 + nt]);
        acc[4 + nt] = mfma16(a2, bb, acc[4 + nt]);
      }
    }
    if (s < 3) {
      propb(bufs[cur ^ 1], bufs[cur], rp, cs, cn);
      __syncthreads();
      cur ^= 1;
    }
  }
  // epilogue: + bias, relu?, write bf16 to buf0
  #pragma unroll
  for (int mt = 0; mt < 3; ++mt)
    #pragma unroll
    for (int nt = 0; nt < 2; ++nt) {
      const int col = (wv * 2 + nt) * 16 + lr;
      const float bias = b[col];
      const f32x4 v = acc[mt * 2 + nt];
      #pragma unroll
      for (int r = 0; r < 4; ++r) {
        const int row = mt * 16 + lg * 4 + r;
        if (row < kN) {
          float x = v[r] + bias;
          if (RELU) x = fmaxf(x, 0.f);
          (Sb + SB0)[row * 136 + col] = f2bf(x);
        }
      }
    }
  __syncthreads();
}

__global__ __launch_bounds__(256, 3) void k_fused(
    const float* __restrict__ feat_seq, const float* __restrict__ x_wls,
    const float* __restrict__ pre_w, const float* __restrict__ pre_b,
    const float* __restrict__ tb1, const float* __restrict__ tb2,
    const float* __restrict__ d1b, const float* __restrict__ d2w,
    const float* __restrict__ d2b, const float* __restrict__ ws,
    const float* __restrict__ sfuse, const float* __restrict__ sgate,
    float* __restrict__ out) {
  __shared__ __align__(16) ushortT S[S_TOT];
  __shared__ float sfrow[kH], sgrow[kH];
  __shared__ float xw[2 * kN];
  __shared__ float featl[kF];
  __shared__ int rp[kN + 1], cs[kE];
  __shared__ float cn[kE];
  __shared__ float part[4][48][2];
  const int tid = threadIdx.x, bw = blockIdx.x;
  const int wv = tid >> 6, lane = tid & 63;
  const int lr = lane & 15, lg = lane >> 4;
  const ushortT* WB = (const ushortT*)(ws + OFF_GI);

  sfrow[tid] = sfuse[bw * kH + tid];
  sgrow[tid] = sgate[bw * kH + tid];
  if (tid < 2 * kN) xw[tid] = x_wls[bw * 2 * kN + tid];
  else if (tid >= 66 && tid < 66 + kF) featl[tid - 66] = feat_seq[bw * kF + (tid - 66)];
  if (tid >= 128 && tid < 128 + kN + 1) rp[tid - 128] = ((const int*)(ws + OFF_ROWPTR))[tid - 128];
  if (tid >= 192) {
    cs[tid - 192] = ((const int*)(ws + OFF_COLSRC))[tid - 192];
    cn[tid - 192] = ws[OFF_COLNORM + (tid - 192)];
  }
  __syncthreads();

  // gin = [feat(8), va, vm] @ pre_w + pre_b  -> buf0 (33x128 bf16)
  for (int idx = tid; idx < kN * kGH; idx += 256) {
    const int n = idx >> 7, j = idx & 127;
    float a = pre_b[j];
    #pragma unroll
    for (int f = 0; f < kF; ++f) a = fmaf(featl[f], pre_w[f * kGH + j], a);
    a = fmaf(xw[n], pre_w[8 * kGH + j], a);
    a = fmaf(xw[kN + n], pre_w[9 * kGH + j], a);
    S[SB0 + n * 136 + j] = f2bf(a);
  }
  __syncthreads();

  tag_mfma<true >(S, WB + WB_TW1, tb1, rp, cs, cn, wv, lane);
  tag_mfma<false>(S, WB + WB_TW2, tb2, rp, cs, cn, wv, lane);

  // ---- g_t = G @ Wc + c -> GT (33x256 bf16) ----
  {
    f32x4 acc[12];
    #pragma unroll
    for (int i = 0; i < 12; ++i) acc[i] = (f32x4){0.f, 0.f, 0.f, 0.f};
    #pragma unroll
    for (int ks = 0; ks < 4; ++ks) {
      const int kof = ks * 32 + lg * 8;
      bs8 a0 = ldb(S + SB0 + (lr) * 136 + kof);
      bs8 a1 = ldb(S + SB0 + (16 + lr) * 136 + kof);
      bs8 a2 = ldb(S + SB0 + (32 + lr) * 136 + kof);
      #pragma unroll
      for (int nt = 0; nt < 4; ++nt) {
        const int col = (wv * 4 + nt) * 16 + lr;
        bs8 bb = ldb(WB + WB_WC + (col << 7) + kof);
        acc[0 + nt] = mfma16(a0, bb, acc[0 + nt]);
        acc[4 + nt] = mfma16(a1, bb, acc[4 + nt]);
        acc[8 + nt] = mfma16(a2, bb, acc[8 + nt]);
      }
    }
    #pragma unroll
    for (int mt = 0; mt < 3; ++mt)
      #pragma unroll
      for (int nt = 0; nt < 4; ++nt) {
        const int col = (wv * 4 + nt) * 16 + lr;
        const float cb = ws[OFF_C + col];
        const f32x4 v = acc[mt * 4 + nt];
        #pragma unroll
        for (int r = 0; r < 4; ++r) {
          const int row = mt * 16 + lg * 4 + r;
          if (row < kN) (S + SGT)[row * 264 + col] = f2bf(v[r] + cb);
        }
      }
    __syncthreads();
  }

  // ---- gate: alpha = sigmoid(GT @ gate_w + sgate); U = a*gt + (1-a)*sfuse -> GT --
  {
    f32x4 acc[12];
    #pragma unroll
    for (int i = 0; i < 12; ++i) acc[i] = (f32x4){0.f, 0.f, 0.f, 0.f};
    #pragma unroll 2
    for (int ks = 0; ks < 8; ++ks) {
      const int kof = ks * 32 + lg * 8;
      bs8 a0 = ldb(S + SGT + (lr) * 264 + kof);
      bs8 a1 = ldb(S + SGT + (16 + lr) * 264 + kof);
      bs8 a2 = ldb(S + SGT + (32 + lr) * 264 + kof);
      #pragma unroll
      for (int nt = 0; nt < 4; ++nt) {
        const int col = (wv * 4 + nt) * 16 + lr;
        bs8 bb = ldb(WB + WB_GATE + (col << 8) + kof);
        acc[0 + nt] = mfma16(a0, bb, acc[0 + nt]);
        acc[4 + nt] = mfma16(a1, bb, acc[4 + nt]);
        acc[8 + nt] = mfma16(a2, bb, acc[8 + nt]);
      }
    }
    // compute U into acc (reads GT), then barrier, then write U over GT
    #pragma unroll
    for (int mt = 0; mt < 3; ++mt)
      #pragma unroll
      for (int nt = 0; nt < 4; ++nt) {
        const int col = (wv * 4 + nt) * 16 + lr;
        const float sg = sgrow[col], sf = sfrow[col];
        #pragma unroll
        for (int r = 0; r < 4; ++r) {
          const int row = mt * 16 + lg * 4 + r;
          if (row < kN) {
            const float al = sigmoidf(acc[mt * 4 + nt][r] + sg);
            const float gt = bf2f((S + SGT)[row * 264 + col]);
            acc[mt * 4 + nt][r] = al * gt + (1.f - al) * sf;
          }
        }
      }
    __syncthreads();
    #pragma unroll
    for (int mt = 0; mt < 3; ++mt)
      #pragma unroll
      for (int nt = 0; nt < 4; ++nt) {
        const int col = (wv * 4 + nt) * 16 + lr;
        #pragma unroll
        for (int r = 0; r < 4; ++r) {
          const int row = mt * 16 + lg * 4 + r;
          if (row < kN) (S + SGT)[row * 264 + col] = f2bf(acc[mt * 4 + nt][r]);
        }
      }
    __syncthreads();
  }

  // ---- d1: V = relu(U @ d1w + d1b); d2 (256->2) + residual ----
  {
    f32x4 acc[12];
    #pragma unroll
    for (int i = 0; i < 12; ++i) acc[i] = (f32x4){0.f, 0.f, 0.f, 0.f};
    #pragma unroll 2
    for (int ks = 0; ks < 8; ++ks) {
      const int kof = ks * 32 + lg * 8;
      bs8 a0 = ldb(S + SGT + (lr) * 264 + kof);
      bs8 a1 = ldb(S + SGT + (16 + lr) * 264 + kof);
      bs8 a2 = ldb(S + SGT + (32 + lr) * 264 + kof);
      #pragma unroll
      for (int nt = 0; nt < 4; ++nt) {
        const int col = (wv * 4 + nt) * 16 + lr;
        bs8 bb = ldb(WB + WB_D1 + (col << 8) + kof);
        acc[0 + nt] = mfma16(a0, bb, acc[0 + nt]);
        acc[4 + nt] = mfma16(a1, bb, acc[4 + nt]);
        acc[8 + nt] = mfma16(a2, bb, acc[8 + nt]);
      }
    }
    float p0[3][4], p1[3][4];
    #pragma unroll
    for (int mt = 0; mt < 3; ++mt)
      #pragma unroll
      for (int r = 0; r < 4; ++r) { p0[mt][r] = 0.f; p1[mt][r] = 0.f; }
    #pragma unroll
    for (int nt = 0; nt < 4; ++nt) {
      const int col = (wv * 4 + nt) * 16 + lr;
      const float db = d1b[col];
      const float2 dp = *reinterpret_cast<const float2*>(d2w + col * 2);
      #pragma unroll
      for (int mt = 0; mt < 3; ++mt)
        #pragma unroll
        for (int r = 0; r < 4; ++r) {
          const float v = fmaxf(acc[mt * 4 + nt][r] + db, 0.f);
          p0[mt][r] = fmaf(v, dp.x, p0[mt][r]);
          p1[mt][r] = fmaf(v, dp.y, p1[mt][r]);
        }
    }
    #pragma unroll
    for (int mt = 0; mt < 3; ++mt)
      #pragma unroll
      for (int r = 0; r < 4; ++r) {
        #pragma unroll
        for (int off = 1; off < 16; off <<= 1) {
          p0[mt][r] += __shfl_xor(p0[mt][r], off, 64);
          p1[mt][r] += __shfl_xor(p1[mt][r], off, 64);
        }
      }
    if (lr == 0) {
      #pragma unroll
      for (int mt = 0; mt < 3; ++mt)
        #pragma unroll
        for (int r = 0; r < 4; ++r) {
          const int row = mt * 16 + lg * 4 + r;
          part[wv][row][0] = p0[mt][r];
          part[wv][row][1] = p1[mt][r];
        }
    }
    __syncthreads();
    if (tid < 66) {
      const int c = tid >= 33 ? 1 : 0;
      const int n = tid - 33 * c;
      float s = d2b[c];
      #pragma unroll
      for (int w = 0; w < 4; ++w) s += part[w][n][c];
      out[bw * 66 + tid] = xw[tid] + s;
    }
  }
}

extern "C" void kernel_launch(void* const* d_in, const int* in_sizes, int n_in,
                              void* d_out, int out_size, void* d_ws, size_t ws_size,
                              hipStream_t stream) {
  const float* r_seq  = (const float*)d_in[0];
  const float* feat   = (const float*)d_in[1];
  const float* x_wls  = (const float*)d_in[2];
  const int*   eidx   = (const int*)d_in[3];
  const float* ew     = (const float*)d_in[4];
  const float* pre_w  = (const float*)d_in[5];
  const float* pre_b  = (const float*)d_in[6];
  const float* tag_w1 = (const float*)d_in[7];
  const float* tag_b1 = (const float*)d_in[8];
  const float* tag_w2 = (const float*)d_in[9];
  const float* tag_b2 = (const float*)d_in[10];
  const float* post_w = (const float*)d_in[11];
  const float* post_b = (const float*)d_in[12];
  const float* tp_w1  = (const float*)d_in[13];
  const float* tp_b1  = (const float*)d_in[14];
  const float* tp_w2  = (const float*)d_in[15];
  const float* tp_b2  = (const float*)d_in[16];
  const float* wih0   = (const float*)d_in[17];
  const float* whh0   = (const float*)d_in[18];
  const float* bih0   = (const float*)d_in[19];
  const float* bhh0   = (const float*)d_in[20];
  const float* wih1   = (const float*)d_in[21];
  const float* whh1   = (const float*)d_in[22];
  const float* bih1   = (const float*)d_in[23];
  const float* bhh1   = (const float*)d_in[24];
  const float* fg_w   = (const float*)d_in[25];
  const float* fg_b   = (const float*)d_in[26];
  const float* fs_w   = (const float*)d_in[27];
  const float* fs_b   = (const float*)d_in[28];
  const float* gate_w = (const float*)d_in[29];
  const float* gate_b = (const float*)d_in[30];
  const float* d1_w   = (const float*)d_in[31];
  const float* d1_b   = (const float*)d_in[32];
  const float* d2_w   = (const float*)d_in[33];
  const float* d2_b   = (const float*)d_in[34];
  float* ws = (float*)d_ws;
  float* outp = (float*)d_out;

  k_prep<<<1, 64, 0, stream>>>(eidx, ew, ws);
  k_wcfold<<<kGH + 1, kH, 0, stream>>>(post_w, post_b, fg_w, fg_b, ws);
  k_wq<<<1536, 256, 0, stream>>>(whh0, whh1, ws);
  k_tpmlp<<<kBW / 8, 256, 0, stream>>>(r_seq, x_wls, tp_w1, tp_b1, tp_w2, tp_b2,
                                       ws + OFF_SPRE);
  k_gigemm<<<kBW / 8, 768, 0, stream>>>(ws + OFF_SPRE, wih0, bih0, ws + OFF_GI);
  k_scan<<<32, 768, 0, stream>>>(ws + OFF_GI, ws + OFF_WQ0, bhh0, ws + OFF_SPRE);
  k_gigemm<<<kBW / 8, 768, 0, stream>>>(ws + OFF_SPRE, wih1, bih1, ws + OFF_GI);
  k_scan<<<32, 768, 0, stream>>>(ws + OFF_GI, ws + OFF_WQ1, bhh1, ws + OFF_SPRE);
  // GI region is now dead -> bf16 B-fragment weights for k_fused
  k_wprep<<<(WB_TOT + 255) / 256, 256, 0, stream>>>(tag_w1, tag_w2, gate_w, d1_w, ws);
  k_fsgate<<<kBW / 8, 256, 0, stream>>>(ws + OFF_SPRE, fs_w, fs_b, gate_w, gate_b,
                                        ws + OFF_SFUSE, ws + OFF_SGATE);
  k_fused<<<kBW, 256, 0, stream>>>(feat, x_wls, pre_w, pre_b, tag_b1, tag_b2,
                                   d1_b, d2_w, d2_b, ws, ws + OFF_SFUSE,
                                   ws + OFF_SGATE, outp);
}

// Round 4
// 1055.584 us; speedup vs baseline: 6.5538x; 2.0767x over previous
//
#include <hip/hip_runtime.h>
#include <hip/hip_fp16.h>
#include <cmath>

#define DEV __device__ __forceinline__

typedef unsigned short ushortT;
typedef short bs8 __attribute__((ext_vector_type(8)));
typedef float f32x4 __attribute__((ext_vector_type(4)));
typedef _Float16 f16x2 __attribute__((ext_vector_type(2)));

constexpr int kBW = 4096;          // B*W
constexpr int kM = 100, kF = 8, kN = 33, kH = 256, kGH = 128, kE = 64;

// ws offsets (in floats)
constexpr int OFF_ROWPTR  = 0;       // 34 int
constexpr int OFF_COLSRC  = 64;      // 64 int
constexpr int OFF_COLNORM = 128;     // 64 f
constexpr int OFF_C       = 192;     // 256 f (folded bias)
constexpr int OFF_WC      = 512;     // 128*256 f (post_w@fg_w)
constexpr int OFF_SPRE    = 33280;               // 4096*256 (s_pre -> s0 -> s1)
constexpr int OFF_GI      = OFF_SPRE + kBW * kH; // 4096*768 f
constexpr int OFF_SFUSE   = OFF_GI + kBW * 3 * kH;  // 4096*256 f
constexpr int OFF_SGATE   = OFF_SFUSE + kBW * kH;   // 4096*256 f
// scan weights (f16 pairs, [k/2][j] u32) live in SFUSE region (dead until
// k_fsgate, which runs after both scans):
constexpr int OFF_WQ0     = OFF_SFUSE;            // 98304 u32
constexpr int OFF_WQ1     = OFF_SFUSE + 98304;    // 98304 u32
// bf16 B-fragment weights for k_fused live in GI region (dead after scans):
// ushort offsets within (ushort*)(ws + OFF_GI):
constexpr int WB_TW1  = 0;        // 4*128*128
constexpr int WB_TW2  = 65536;    // 4*128*128
constexpr int WB_WC   = 131072;   // 256 cols x 128 k
constexpr int WB_GATE = 163840;   // 256 cols x 256 k
constexpr int WB_D1   = 229376;   // 256 cols x 256 k
constexpr int WB_TOT  = 294912;

DEV float sigmoidf(float x) { return 1.0f / (1.0f + expf(-x)); }

DEV ushortT f2bf(float x) {
  unsigned u = __float_as_uint(x);
  unsigned r = u + 0x7fffu + ((u >> 16) & 1u);
  return (ushortT)(r >> 16);
}
DEV float bf2f(ushortT u) { return __uint_as_float(((unsigned)u) << 16); }

DEV f32x4 mfma16(bs8 a, bs8 b, f32x4 c) {
  return __builtin_amdgcn_mfma_f32_16x16x32_bf16(a, b, c, 0, 0, 0);
}
DEV bs8 ldb(const ushortT* p) { return *reinterpret_cast<const bs8*>(p); }

#if __has_builtin(__builtin_amdgcn_fdot2)
DEV float dot2(unsigned w, unsigned hp, float acc) {
  f16x2 wv = __builtin_bit_cast(f16x2, w);
  f16x2 hv = __builtin_bit_cast(f16x2, hp);
  return __builtin_amdgcn_fdot2(wv, hv, acc, false);
}
#else
DEV float dot2(unsigned w, unsigned hp, float acc) {
  f16x2 wv = __builtin_bit_cast(f16x2, w);
  f16x2 hv = __builtin_bit_cast(f16x2, hp);
  acc = fmaf((float)wv.x, (float)hv.x, acc);
  acc = fmaf((float)wv.y, (float)hv.y, acc);
  return acc;
}
#endif

// ---------------- graph prep: degree norm + CSR by dst ---------------------------
__global__ void k_prep(const int* __restrict__ ei, const float* __restrict__ ew,
                       float* __restrict__ ws) {
  if (blockIdx.x != 0 || threadIdx.x != 0) return;
  int* rowptr = (int*)(ws + OFF_ROWPTR);
  int* colsrc = (int*)(ws + OFF_COLSRC);
  float* colnorm = ws + OFF_COLNORM;
  const int* src = ei;
  const int* dst = ei + kE;
  float deg[kN]; int cnt[kN];
  for (int n = 0; n < kN; ++n) { deg[n] = 0.f; cnt[n] = 0; }
  for (int e = 0; e < kE; ++e) { deg[dst[e]] += ew[e]; cnt[dst[e]]++; }
  float dinv[kN];
  for (int n = 0; n < kN; ++n) dinv[n] = deg[n] > 0.f ? 1.0f / sqrtf(deg[n]) : 0.f;
  int pos[kN];
  int run = 0;
  for (int n = 0; n < kN; ++n) { rowptr[n] = run; pos[n] = run; run += cnt[n]; }
  rowptr[kN] = run;
  for (int e = 0; e < kE; ++e) {
    int d = dst[e];
    int p = pos[d]++;
    colsrc[p] = src[e];
    colnorm[p] = dinv[src[e]] * ew[e] * dinv[d];
  }
}

// ---------------- fold Wc = post_w @ fg_w (128x256), c = post_b @ fg_w + fg_b -----
__global__ void k_wcfold(const float* __restrict__ post_w, const float* __restrict__ post_b,
                         const float* __restrict__ fg_w, const float* __restrict__ fg_b,
                         float* __restrict__ ws) {
  const int j = threadIdx.x;
  if ((int)blockIdx.x < kGH) {
    const int k = blockIdx.x;
    float a = 0.f;
    #pragma unroll 4
    for (int m = 0; m < kH; ++m) a = fmaf(post_w[k * kH + m], fg_w[m * kH + j], a);
    ws[OFF_WC + k * kH + j] = a;
  } else {
    float a = fg_b[j];
    #pragma unroll 4
    for (int m = 0; m < kH; ++m) a = fmaf(post_b[m], fg_w[m * kH + j], a);
    ws[OFF_C + j] = a;
  }
}

// ---------------- scan weights: whh[k][j] -> f16 pairs wq[(k/2)*768 + j] ----------
__global__ void k_wq(const float* __restrict__ w0, const float* __restrict__ w1,
                     float* __restrict__ ws) {
  const int idx = blockIdx.x * 256 + threadIdx.x;
  if (idx >= 2 * 98304) return;
  const int layer = idx / 98304;
  const int rem = idx - layer * 98304;
  const int p = rem / 768, j = rem - p * 768;
  const float* w = layer ? w1 : w0;
  unsigned* dst = (unsigned*)(ws + (layer ? OFF_WQ1 : OFF_WQ0));
  __half2 v = __floats2half2_rn(w[(2 * p) * 768 + j], w[(2 * p + 1) * 768 + j]);
  dst[rem] = *reinterpret_cast<unsigned*>(&v);
}

// ---------------- bf16 B-fragment weights ([col][k]) for k_fused -----------------
__global__ void k_wprep(const float* __restrict__ tw1, const float* __restrict__ tw2,
                        const float* __restrict__ gatew, const float* __restrict__ d1w,
                        float* __restrict__ ws) {
  const int idx = blockIdx.x * 256 + threadIdx.x;
  if (idx >= WB_TOT) return;
  ushortT* WB = (ushortT*)(ws + OFF_GI);
  float v; int dst;
  if (idx < 65536) {
    int s = idx >> 14, r = idx & 16383, k = r >> 7, col = r & 127;
    v = tw1[(s << 14) + (k << 7) + col]; dst = WB_TW1 + (s << 14) + (col << 7) + k;
  } else if (idx < 131072) {
    int i = idx - 65536; int s = i >> 14, r = i & 16383, k = r >> 7, col = r & 127;
    v = tw2[(s << 14) + (k << 7) + col]; dst = WB_TW2 + (s << 14) + (col << 7) + k;
  } else if (idx < 163840) {
    int i = idx - 131072; int k = i & 127, col = i >> 7;
    v = ws[OFF_WC + (k << 8) + col]; dst = WB_WC + (col << 7) + k;
  } else if (idx < 229376) {
    int i = idx - 163840; int k = i & 255, col = i >> 8;
    v = gatew[(k << 8) + col]; dst = WB_GATE + (col << 8) + k;
  } else {
    int i = idx - 229376; int k = i & 255, col = i >> 8;
    v = d1w[(k << 8) + col]; dst = WB_D1 + (col << 8) + k;
  }
  WB[dst] = f2bf(v);
}

// ---------------- temporal pre-MLP, 8 rows per block ------------------------------
__global__ __launch_bounds__(256) void k_tpmlp(
    const float* __restrict__ r_seq, const float* __restrict__ x_wls,
    const float* __restrict__ w1, const float* __restrict__ b1,
    const float* __restrict__ w2, const float* __restrict__ b2,
    float* __restrict__ sout) {
  __shared__ float inr[8][kM + 2 * kN];  // 8 x 166
  __shared__ float h1[8][kH];
  const int bw0 = blockIdx.x * 8, tid = threadIdx.x;
  #pragma unroll
  for (int r = 0; r < 8; ++r) {
    for (int c = tid; c < kM + 2 * kN; c += 256)
      inr[r][c] = (c < kM) ? r_seq[(bw0 + r) * kM + c]
                           : x_wls[(bw0 + r) * 2 * kN + (c - kM)];
  }
  __syncthreads();
  float acc[8];
  {
    const float bb = b1[tid];
    #pragma unroll
    for (int r = 0; r < 8; ++r) acc[r] = bb;
  }
  for (int k = 0; k < kM + 2 * kN; ++k) {
    const float w = w1[k * kH + tid];
    #pragma unroll
    for (int r = 0; r < 8; ++r) acc[r] = fmaf(inr[r][k], w, acc[r]);
  }
  #pragma unroll
  for (int r = 0; r < 8; ++r) h1[r][tid] = fmaxf(acc[r], 0.f);
  __syncthreads();
  {
    const float bb = b2[tid];
    #pragma unroll
    for (int r = 0; r < 8; ++r) acc[r] = bb;
  }
  #pragma unroll 2
  for (int k = 0; k < kH; ++k) {
    const float w = w2[k * kH + tid];
    #pragma unroll
    for (int r = 0; r < 8; ++r) acc[r] = fmaf(h1[r][k], w, acc[r]);
  }
  #pragma unroll
  for (int r = 0; r < 8; ++r) sout[(bw0 + r) * kH + tid] = fmaxf(acc[r], 0.f);
}

// ---------------- gi = s @ wih + bih, 8 rows per block ----------------------------
__global__ __launch_bounds__(768) void k_gigemm(
    const float* __restrict__ sin, const float* __restrict__ wih,
    const float* __restrict__ bih, float* __restrict__ gi) {
  __shared__ float sr[8][kH];
  const int bw0 = blockIdx.x * 8, tid = threadIdx.x;
  for (int i = tid; i < 8 * kH; i += 768) sr[i >> 8][i & 255] = sin[bw0 * kH + i];
  __syncthreads();
  float acc[8];
  {
    const float bb = bih[tid];
    #pragma unroll
    for (int r = 0; r < 8; ++r) acc[r] = bb;
  }
  #pragma unroll 2
  for (int k = 0; k < kH; ++k) {
    const float w = wih[k * 768 + tid];
    #pragma unroll
    for (int r = 0; r < 8; ++r) acc[r] = fmaf(sr[r][k], w, acc[r]);
  }
  #pragma unroll
  for (int r = 0; r < 8; ++r) gi[(bw0 + r) * 768 + tid] = acc[r];
}

// ---------------- GRU scan: weights in VGPRs (f16 pairs), h packed in LDS ---------
// Thread j owns output column j. 128 u32 weight regs; 12 waves/CU
// (__launch_bounds__(768,3) caps VGPR at ~170 so the array stays in regs).
__global__ __launch_bounds__(768, 3) void k_scan(
    const float* __restrict__ gi, const float* __restrict__ wq,
    const float* __restrict__ bhh, float* __restrict__ sout) {
  __shared__ float h[kH];
  __shared__ __align__(16) unsigned hpk[kH / 2];  // f16 pairs of h
  __shared__ float gh[3 * kH];
  const int b = blockIdx.x, tid = threadIdx.x;
  const unsigned* wqp = (const unsigned*)wq;
  unsigned wr[128];
  #pragma unroll
  for (int p = 0; p < 128; ++p) wr[p] = wqp[p * 768 + tid];
  if (tid < kH) h[tid] = 0.f;
  if (tid < kH / 2) hpk[tid] = 0u;
  __syncthreads();
  const float bb = bhh[tid];
  for (int t = 0; t < 128; ++t) {
    const float* girow = gi + (b * 128 + t) * 768;
    float a0 = bb, a1 = 0.f, a2 = 0.f, a3 = 0.f;
    #pragma unroll
    for (int q = 0; q < 32; ++q) {
      const uint4 hp = *reinterpret_cast<const uint4*>(hpk + 4 * q);
      a0 = dot2(wr[4 * q + 0], hp.x, a0);
      a1 = dot2(wr[4 * q + 1], hp.y, a1);
      a2 = dot2(wr[4 * q + 2], hp.z, a2);
      a3 = dot2(wr[4 * q + 3], hp.w, a3);
    }
    gh[tid] = (a0 + a1) + (a2 + a3);
    __syncthreads();
    if (tid < kH) {
      float r = sigmoidf(girow[tid] + gh[tid]);
      float z = sigmoidf(girow[kH + tid] + gh[kH + tid]);
      float n = tanhf(fmaf(r, gh[2 * kH + tid], girow[2 * kH + tid]));
      float hn = (1.f - z) * n + z * h[tid];
      h[tid] = hn;
      reinterpret_cast<__half*>(hpk)[tid] = __float2half(hn);
      sout[(b * 128 + t) * kH + tid] = hn;
    }
    __syncthreads();
  }
}

// ---------------- sfuse/sgate, 8 rows per block -----------------------------------
__global__ __launch_bounds__(256) void k_fsgate(
    const float* __restrict__ s1, const float* __restrict__ fsw,
    const float* __restrict__ fsb, const float* __restrict__ gw,
    const float* __restrict__ gb, float* __restrict__ sfuse,
    float* __restrict__ sgate) {
  __shared__ float sr[8][kH], sf[8][kH];
  const int bw0 = blockIdx.x * 8, tid = threadIdx.x;
  for (int i = tid; i < 8 * kH; i += 256) sr[i >> 8][i & 255] = s1[bw0 * kH + i];
  __syncthreads();
  float acc[8];
  {
    const float bb = fsb[tid];
    #pragma unroll
    for (int r = 0; r < 8; ++r) acc[r] = bb;
  }
  #pragma unroll 2
  for (int k = 0; k < kH; ++k) {
    const float w = fsw[k * kH + tid];
    #pragma unroll
    for (int r = 0; r < 8; ++r) acc[r] = fmaf(sr[r][k], w, acc[r]);
  }
  #pragma unroll
  for (int r = 0; r < 8; ++r) { sf[r][tid] = acc[r]; sfuse[(bw0 + r) * kH + tid] = acc[r]; }
  __syncthreads();
  {
    const float bb = gb[tid];
    #pragma unroll
    for (int r = 0; r < 8; ++r) acc[r] = bb;
  }
  #pragma unroll 2
  for (int k = 0; k < kH; ++k) {
    const float w = gw[(kH + k) * kH + tid];
    #pragma unroll
    for (int r = 0; r < 8; ++r) acc[r] = fmaf(sf[r][k], w, acc[r]);
  }
  #pragma unroll
  for (int r = 0; r < 8; ++r) sgate[(bw0 + r) * kH + tid] = acc[r];
}

// ================= fused GNN + gate + decoder (MFMA bf16) =========================
// 256 threads = 4 waves. Activations bf16 in LDS:
//   buf0/buf1: 36 rows x 136 (K=128, +8 pad); GT: rows x 264 (K=256, +8 pad).
// A-frag: row = mt*16 + (lane&15), k = kstep*32 + (lane>>4)*8 (ds_read_b128).
// B-frag: [col][k] bf16 in global (L2); col = ntile*16 + (lane&15).
// C/D: col = lane&15 (+16*nt), row = mt*16 + (lane>>4)*4 + reg.

constexpr int SB0 = 0;
constexpr int SB1 = 36 * 136;           // 4896
constexpr int SGT = 2 * 36 * 136;       // 9792
constexpr int S_TOT = SGT + 48 * 264;   // 22464 ushorts = 44928 B

// dst(rows<33) = P @ src, bf16 pairs
DEV void propb(ushortT* __restrict__ dst, const ushortT* __restrict__ src,
               const int* __restrict__ rp, const int* __restrict__ cs,
               const float* __restrict__ cn) {
  for (int idx = threadIdx.x; idx < kN * 64; idx += 256) {
    const int n = idx >> 6, j2 = idx & 63;
    float a0 = 0.f, a1 = 0.f;
    const int p1 = rp[n + 1];
    for (int p = rp[n]; p < p1; ++p) {
      const unsigned v = *(const unsigned*)(src + cs[p] * 136 + 2 * j2);
      const float w = cn[p];
      a0 = fmaf(__uint_as_float(v << 16), w, a0);
      a1 = fmaf(__uint_as_float(v & 0xffff0000u), w, a1);
    }
    *(unsigned*)(dst + n * 136 + 2 * j2) = (unsigned)f2bf(a0) | ((unsigned)f2bf(a1) << 16);
  }
}

// tag pass: buf0(h) -> buf0(out), using buf1 as scratch. W stacked 4x[col][k].
template <bool RELU>
DEV void tag_mfma(ushortT* __restrict__ Sb, const ushortT* __restrict__ WT,
                  const float* __restrict__ b, const int* __restrict__ rp,
                  const int* __restrict__ cs, const float* __restrict__ cn,
                  int wv, int lane) {
  const int lr = lane & 15, lg = lane >> 4;
  f32x4 acc[6];
  #pragma unroll
  for (int i = 0; i < 6; ++i) acc[i] = (f32x4){0.f, 0.f, 0.f, 0.f};
  ushortT* bufs[2] = {Sb + SB0, Sb + SB1};
  int cur = 0;
  #pragma unroll
  for (int s = 0; s < 4; ++s) {
    const ushortT* A = bufs[cur];
    #pragma unroll
    for (int ks = 0; ks < 4; ++ks) {
      const int kof = ks * 32 + lg * 8;
      bs8 a0 = ldb(A + (lr) * 136 + kof);
      bs8 a1 = ldb(A + (16 + lr) * 136 + kof);
      bs8 a2 = ldb(A + (32 + lr) * 136 + kof);
      #pragma unroll
      for (int nt = 0; nt < 2; ++nt) {
        const int col = (wv * 2 + nt) * 16 + lr;
        bs8 bb = ldb(WT + (s << 14) + (col << 7) + kof);
        acc[0 + nt] = mfma16(a0, bb, acc[0 + nt]);
        acc[2 + nt] = mfma16(a1, bb, acc[2 + nt]);
        acc[4 + nt] = mfma16(a2, bb, acc[4 + nt]);
      }
    }
    if (s < 3) {
      propb(bufs[cur ^ 1], bufs[cur], rp, cs, cn);
      __syncthreads();
      cur ^= 1;
    }
  }
  // epilogue: + bias, relu?, write bf16 to buf0
  #pragma unroll
  for (int mt = 0; mt < 3; ++mt)
    #pragma unroll
    for (int nt = 0; nt < 2; ++nt) {
      const int col = (wv * 2 + nt) * 16 + lr;
      const float bias = b[col];
      const f32x4 v = acc[mt * 2 + nt];
      #pragma unroll
      for (int r = 0; r < 4; ++r) {
        const int row = mt * 16 + lg * 4 + r;
        if (row < kN) {
          float x = v[r] + bias;
          if (RELU) x = fmaxf(x, 0.f);
          (Sb + SB0)[row * 136 + col] = f2bf(x);
        }
      }
    }
  __syncthreads();
}

__global__ __launch_bounds__(256, 3) void k_fused(
    const float* __restrict__ feat_seq, const float* __restrict__ x_wls,
    const float* __restrict__ pre_w, const float* __restrict__ pre_b,
    const float* __restrict__ tb1, const float* __restrict__ tb2,
    const float* __restrict__ d1b, const float* __restrict__ d2w,
    const float* __restrict__ d2b, const float* __restrict__ ws,
    const float* __restrict__ sfuse, const float* __restrict__ sgate,
    float* __restrict__ out) {
  __shared__ __align__(16) ushortT S[S_TOT];
  __shared__ float sfrow[kH], sgrow[kH];
  __shared__ float xw[2 * kN];
  __shared__ float featl[kF];
  __shared__ int rp[kN + 1], cs[kE];
  __shared__ float cn[kE];
  __shared__ float part[4][48][2];
  const int tid = threadIdx.x, bw = blockIdx.x;
  const int wv = tid >> 6, lane = tid & 63;
  const int lr = lane & 15, lg = lane >> 4;
  const ushortT* WB = (const ushortT*)(ws + OFF_GI);

  sfrow[tid] = sfuse[bw * kH + tid];
  sgrow[tid] = sgate[bw * kH + tid];
  if (tid < 2 * kN) xw[tid] = x_wls[bw * 2 * kN + tid];
  else if (tid >= 66 && tid < 66 + kF) featl[tid - 66] = feat_seq[bw * kF + (tid - 66)];
  if (tid >= 128 && tid < 128 + kN + 1) rp[tid - 128] = ((const int*)(ws + OFF_ROWPTR))[tid - 128];
  if (tid >= 192) {
    cs[tid - 192] = ((const int*)(ws + OFF_COLSRC))[tid - 192];
    cn[tid - 192] = ws[OFF_COLNORM + (tid - 192)];
  }
  __syncthreads();

  // gin = [feat(8), va, vm] @ pre_w + pre_b  -> buf0 (33x128 bf16)
  for (int idx = tid; idx < kN * kGH; idx += 256) {
    const int n = idx >> 7, j = idx & 127;
    float a = pre_b[j];
    #pragma unroll
    for (int f = 0; f < kF; ++f) a = fmaf(featl[f], pre_w[f * kGH + j], a);
    a = fmaf(xw[n], pre_w[8 * kGH + j], a);
    a = fmaf(xw[kN + n], pre_w[9 * kGH + j], a);
    S[SB0 + n * 136 + j] = f2bf(a);
  }
  __syncthreads();

  tag_mfma<true >(S, WB + WB_TW1, tb1, rp, cs, cn, wv, lane);
  tag_mfma<false>(S, WB + WB_TW2, tb2, rp, cs, cn, wv, lane);

  // ---- g_t = G @ Wc + c -> GT (33x256 bf16) ----
  {
    f32x4 acc[12];
    #pragma unroll
    for (int i = 0; i < 12; ++i) acc[i] = (f32x4){0.f, 0.f, 0.f, 0.f};
    #pragma unroll
    for (int ks = 0; ks < 4; ++ks) {
      const int kof = ks * 32 + lg * 8;
      bs8 a0 = ldb(S + SB0 + (lr) * 136 + kof);
      bs8 a1 = ldb(S + SB0 + (16 + lr) * 136 + kof);
      bs8 a2 = ldb(S + SB0 + (32 + lr) * 136 + kof);
      #pragma unroll
      for (int nt = 0; nt < 4; ++nt) {
        const int col = (wv * 4 + nt) * 16 + lr;
        bs8 bb = ldb(WB + WB_WC + (col << 7) + kof);
        acc[0 + nt] = mfma16(a0, bb, acc[0 + nt]);
        acc[4 + nt] = mfma16(a1, bb, acc[4 + nt]);
        acc[8 + nt] = mfma16(a2, bb, acc[8 + nt]);
      }
    }
    #pragma unroll
    for (int mt = 0; mt < 3; ++mt)
      #pragma unroll
      for (int nt = 0; nt < 4; ++nt) {
        const int col = (wv * 4 + nt) * 16 + lr;
        const float cb = ws[OFF_C + col];
        const f32x4 v = acc[mt * 4 + nt];
        #pragma unroll
        for (int r = 0; r < 4; ++r) {
          const int row = mt * 16 + lg * 4 + r;
          if (row < kN) (S + SGT)[row * 264 + col] = f2bf(v[r] + cb);
        }
      }
    __syncthreads();
  }

  // ---- gate: alpha = sigmoid(GT @ gate_w + sgate); U = a*gt + (1-a)*sfuse -> GT --
  {
    f32x4 acc[12];
    #pragma unroll
    for (int i = 0; i < 12; ++i) acc[i] = (f32x4){0.f, 0.f, 0.f, 0.f};
    #pragma unroll 2
    for (int ks = 0; ks < 8; ++ks) {
      const int kof = ks * 32 + lg * 8;
      bs8 a0 = ldb(S + SGT + (lr) * 264 + kof);
      bs8 a1 = ldb(S + SGT + (16 + lr) * 264 + kof);
      bs8 a2 = ldb(S + SGT + (32 + lr) * 264 + kof);
      #pragma unroll
      for (int nt = 0; nt < 4; ++nt) {
        const int col = (wv * 4 + nt) * 16 + lr;
        bs8 bb = ldb(WB + WB_GATE + (col << 8) + kof);
        acc[0 + nt] = mfma16(a0, bb, acc[0 + nt]);
        acc[4 + nt] = mfma16(a1, bb, acc[4 + nt]);
        acc[8 + nt] = mfma16(a2, bb, acc[8 + nt]);
      }
    }
    // compute U into acc (reads GT), then barrier, then write U over GT
    #pragma unroll
    for (int mt = 0; mt < 3; ++mt)
      #pragma unroll
      for (int nt = 0; nt < 4; ++nt) {
        const int col = (wv * 4 + nt) * 16 + lr;
        const float sg = sgrow[col], sf = sfrow[col];
        #pragma unroll
        for (int r = 0; r < 4; ++r) {
          const int row = mt * 16 + lg * 4 + r;
          if (row < kN) {
            const float al = sigmoidf(acc[mt * 4 + nt][r] + sg);
            const float gt = bf2f((S + SGT)[row * 264 + col]);
            acc[mt * 4 + nt][r] = al * gt + (1.f - al) * sf;
          }
        }
      }
    __syncthreads();
    #pragma unroll
    for (int mt = 0; mt < 3; ++mt)
      #pragma unroll
      for (int nt = 0; nt < 4; ++nt) {
        const int col = (wv * 4 + nt) * 16 + lr;
        #pragma unroll
        for (int r = 0; r < 4; ++r) {
          const int row = mt * 16 + lg * 4 + r;
          if (row < kN) (S + SGT)[row * 264 + col] = f2bf(acc[mt * 4 + nt][r]);
        }
      }
    __syncthreads();
  }

  // ---- d1: V = relu(U @ d1w + d1b); d2 (256->2) + residual ----
  {
    f32x4 acc[12];
    #pragma unroll
    for (int i = 0; i < 12; ++i) acc[i] = (f32x4){0.f, 0.f, 0.f, 0.f};
    #pragma unroll 2
    for (int ks = 0; ks < 8; ++ks) {
      const int kof = ks * 32 + lg * 8;
      bs8 a0 = ldb(S + SGT + (lr) * 264 + kof);
      bs8 a1 = ldb(S + SGT + (16 + lr) * 264 + kof);
      bs8 a2 = ldb(S + SGT + (32 + lr) * 264 + kof);
      #pragma unroll
      for (int nt = 0; nt < 4; ++nt) {
        const int col = (wv * 4 + nt) * 16 + lr;
        bs8 bb = ldb(WB + WB_D1 + (col << 8) + kof);
        acc[0 + nt] = mfma16(a0, bb, acc[0 + nt]);
        acc[4 + nt] = mfma16(a1, bb, acc[4 + nt]);
        acc[8 + nt] = mfma16(a2, bb, acc[8 + nt]);
      }
    }
    float p0[3][4], p1[3][4];
    #pragma unroll
    for (int mt = 0; mt < 3; ++mt)
      #pragma unroll
      for (int r = 0; r < 4; ++r) { p0[mt][r] = 0.f; p1[mt][r] = 0.f; }
    #pragma unroll
    for (int nt = 0; nt < 4; ++nt) {
      const int col = (wv * 4 + nt) * 16 + lr;
      const float db = d1b[col];
      const float2 dp = *reinterpret_cast<const float2*>(d2w + col * 2);
      #pragma unroll
      for (int mt = 0; mt < 3; ++mt)
        #pragma unroll
        for (int r = 0; r < 4; ++r) {
          const float v = fmaxf(acc[mt * 4 + nt][r] + db, 0.f);
          p0[mt][r] = fmaf(v, dp.x, p0[mt][r]);
          p1[mt][r] = fmaf(v, dp.y, p1[mt][r]);
        }
    }
    #pragma unroll
    for (int mt = 0; mt < 3; ++mt)
      #pragma unroll
      for (int r = 0; r < 4; ++r) {
        #pragma unroll
        for (int off = 1; off < 16; off <<= 1) {
          p0[mt][r] += __shfl_xor(p0[mt][r], off, 64);
          p1[mt][r] += __shfl_xor(p1[mt][r], off, 64);
        }
      }
    if (lr == 0) {
      #pragma unroll
      for (int mt = 0; mt < 3; ++mt)
        #pragma unroll
        for (int r = 0; r < 4; ++r) {
          const int row = mt * 16 + lg * 4 + r;
          part[wv][row][0] = p0[mt][r];
          part[wv][row][1] = p1[mt][r];
        }
    }
    __syncthreads();
    if (tid < 66) {
      const int c = tid >= 33 ? 1 : 0;
      const int n = tid - 33 * c;
      float s = d2b[c];
      #pragma unroll
      for (int w = 0; w < 4; ++w) s += part[w][n][c];
      out[bw * 66 + tid] = xw[tid] + s;
    }
  }
}

extern "C" void kernel_launch(void* const* d_in, const int* in_sizes, int n_in,
                              void* d_out, int out_size, void* d_ws, size_t ws_size,
                              hipStream_t stream) {
  const float* r_seq  = (const float*)d_in[0];
  const float* feat   = (const float*)d_in[1];
  const float* x_wls  = (const float*)d_in[2];
  const int*   eidx   = (const int*)d_in[3];
  const float* ew     = (const float*)d_in[4];
  const float* pre_w  = (const float*)d_in[5];
  const float* pre_b  = (const float*)d_in[6];
  const float* tag_w1 = (const float*)d_in[7];
  const float* tag_b1 = (const float*)d_in[8];
  const float* tag_w2 = (const float*)d_in[9];
  const float* tag_b2 = (const float*)d_in[10];
  const float* post_w = (const float*)d_in[11];
  const float* post_b = (const float*)d_in[12];
  const float* tp_w1  = (const float*)d_in[13];
  const float* tp_b1  = (const float*)d_in[14];
  const float* tp_w2  = (const float*)d_in[15];
  const float* tp_b2  = (const float*)d_in[16];
  const float* wih0   = (const float*)d_in[17];
  const float* whh0   = (const float*)d_in[18];
  const float* bih0   = (const float*)d_in[19];
  const float* bhh0   = (const float*)d_in[20];
  const float* wih1   = (const float*)d_in[21];
  const float* whh1   = (const float*)d_in[22];
  const float* bih1   = (const float*)d_in[23];
  const float* bhh1   = (const float*)d_in[24];
  const float* fg_w   = (const float*)d_in[25];
  const float* fg_b   = (const float*)d_in[26];
  const float* fs_w   = (const float*)d_in[27];
  const float* fs_b   = (const float*)d_in[28];
  const float* gate_w = (const float*)d_in[29];
  const float* gate_b = (const float*)d_in[30];
  const float* d1_w   = (const float*)d_in[31];
  const float* d1_b   = (const float*)d_in[32];
  const float* d2_w   = (const float*)d_in[33];
  const float* d2_b   = (const float*)d_in[34];
  float* ws = (float*)d_ws;
  float* outp = (float*)d_out;

  k_prep<<<1, 64, 0, stream>>>(eidx, ew, ws);
  k_wcfold<<<kGH + 1, kH, 0, stream>>>(post_w, post_b, fg_w, fg_b, ws);
  k_wq<<<768, 256, 0, stream>>>(whh0, whh1, ws);
  k_tpmlp<<<kBW / 8, 256, 0, stream>>>(r_seq, x_wls, tp_w1, tp_b1, tp_w2, tp_b2,
                                       ws + OFF_SPRE);
  k_gigemm<<<kBW / 8, 768, 0, stream>>>(ws + OFF_SPRE, wih0, bih0, ws + OFF_GI);
  k_scan<<<32, 768, 0, stream>>>(ws + OFF_GI, ws + OFF_WQ0, bhh0, ws + OFF_SPRE);
  k_gigemm<<<kBW / 8, 768, 0, stream>>>(ws + OFF_SPRE, wih1, bih1, ws + OFF_GI);
  k_scan<<<32, 768, 0, stream>>>(ws + OFF_GI, ws + OFF_WQ1, bhh1, ws + OFF_SPRE);
  // GI region is now dead -> bf16 B-fragment weights for k_fused
  k_wprep<<<(WB_TOT + 255) / 256, 256, 0, stream>>>(tag_w1, tag_w2, gate_w, d1_w, ws);
  k_fsgate<<<kBW / 8, 256, 0, stream>>>(ws + OFF_SPRE, fs_w, fs_b, gate_w, gate_b,
                                        ws + OFF_SFUSE, ws + OFF_SGATE);
  k_fused<<<kBW, 256, 0, stream>>>(feat, x_wls, pre_w, pre_b, tag_b1, tag_b2,
                                   d1_b, d2_w, d2_b, ws, ws + OFF_SFUSE,
                                   ws + OFF_SGATE, outp);
}